// Round 2
// baseline (478.899 us; speedup 1.0000x reference)
//
#include <hip/hip_runtime.h>
#include <hip/hip_bf16.h>

#define N_NODES 20000
#define E_EDGES 640000
#define DIM 128
#define CAP 96    // Poisson(32) max degree ~65; 96 is >10-sigma safe
#define EPB 64    // edges per tile in edge_kernel
#define NPB 8     // nodes per block (edge_kernel AND node_kernel)
#define XST 264   // padded ushort stride for [64][256] LDS tile

typedef __attribute__((ext_vector_type(8))) short bf16x8;
typedef __attribute__((ext_vector_type(4))) float f32x4;

#define LOG2E 1.44269504f
__device__ __forceinline__ float fsilu(float x) {
    return x * __builtin_amdgcn_rcpf(1.f + __builtin_amdgcn_exp2f(-LOG2E * x));
}
__device__ __forceinline__ float fsig(float x) {
    return __builtin_amdgcn_rcpf(1.f + __builtin_amdgcn_exp2f(-LOG2E * x));
}

__device__ __forceinline__ unsigned short f2bf(float x) {
    union { float f; unsigned u; } v; v.f = x;
    unsigned r = (v.u + 0x7fffu + ((v.u >> 16) & 1u)) >> 16;
    return (unsigned short)r;
}
__device__ __forceinline__ float bf2f(unsigned short s) {
    union { unsigned u; float f; } v; v.u = ((unsigned)s) << 16;
    return v.f;
}
// pack two floats to packed bf16 {lo,hi} with round-half-up
__device__ __forceinline__ unsigned pack_bf16(float lo, float hi) {
    union { float f; unsigned u; } a, b; a.f = lo; b.f = hi;
    unsigned ul = a.u + 0x8000u, uh = b.u + 0x8000u;
    return __builtin_amdgcn_perm(uh, ul, 0x07060302u);
}

// ------- fused pre-kernel: weight prep (64) + lin (625) + adj build (2500) -------
#define PRE_PREP_BLOCKS 64
#define PRE_LIN_BLOCKS  625   // 32 nodes per block
#define PRE_ADJ_BLOCKS  2500
__global__ __launch_bounds__(256) void pre_kernel(
    const float* __restrict__ w1, const float* __restrict__ w2,
    unsigned short* __restrict__ w1b, float* __restrict__ w1p,
    unsigned short* __restrict__ w2b,
    const float* __restrict__ h, const float* __restrict__ lw,
    const float* __restrict__ lb, float* __restrict__ x,
    unsigned short* __restrict__ xb,
    const int* __restrict__ edges,
    const float* __restrict__ dist, const float* __restrict__ emask,
    int* __restrict__ cnt,
    int* __restrict__ adjc, float2* __restrict__ dm, int E) {
    __shared__ float hs[32][128];
    int b = blockIdx.x;
    int t = threadIdx.x;

    if (b < PRE_PREP_BLOCKS) {
        int i = b * 256 + t;
        const int stride = PRE_PREP_BLOCKS * 256;
        for (int idx = i; idx < 256 * 256; idx += stride) {
            int o = idx >> 8, k = idx & 255;
            w1b[idx] = f2bf(w1[o * 257 + k]);
        }
        // w2b k-order permuted: within each 32-chunk b2: pos b2+2l <- k=b2+l ; b2+2l+1 <- k=b2+16+l
        for (int idx = i; idx < 128 * 256; idx += stride) {
            int n2 = idx >> 8, p = idx & 255;
            int bb = p & ~31, off = p & 31;
            int ksrc = bb + (off >> 1) + ((off & 1) << 4);
            w2b[idx] = f2bf(w2[n2 * 256 + ksrc]);
        }
        // w1last in the SAME permuted order as the a1 LDS tile / w2b k-order
        for (int idx = i; idx < 256; idx += stride) {
            int bb = idx & ~31, off = idx & 31;
            int ksrc = bb + (off >> 1) + ((off & 1) << 4);
            w1p[idx] = w1[ksrc * 257 + 256];
        }
    } else if (b < PRE_PREP_BLOCKS + PRE_LIN_BLOCKS) {
        int nb = b - PRE_PREP_BLOCKS;
        int n0 = nb * 32;
        int ch = t & 127, g = t >> 7;   // g in {0,1}, 16 nodes each
#pragma unroll
        for (int j = 0; j < 16; ++j) hs[g * 16 + j][ch] = h[(size_t)(n0 + g * 16 + j) * DIM + ch];
        __syncthreads();
        float acc[16];
#pragma unroll
        for (int j = 0; j < 16; ++j) acc[j] = 0.f;
        for (int kc = 0; kc < 128; kc += 4) {
            float4 wv = *(const float4*)&lw[(size_t)ch * DIM + kc];
#pragma unroll
            for (int j = 0; j < 16; ++j)
                acc[j] += wv.x * hs[g * 16 + j][kc] + wv.y * hs[g * 16 + j][kc + 1]
                        + wv.z * hs[g * 16 + j][kc + 2] + wv.w * hs[g * 16 + j][kc + 3];
        }
        float bias = lb[ch];
#pragma unroll
        for (int j = 0; j < 16; ++j) {
            float v = acc[j] + bias;
            int n = n0 + g * 16 + j;
            x[(size_t)n * DIM + ch] = v;
            xb[(size_t)n * DIM + ch] = f2bf(v);
        }
    } else {
        int e = (b - PRE_PREP_BLOCKS - PRE_LIN_BLOCKS) * 256 + t;
        if (e < E) {
            int r = edges[e];
            int col = edges[E + e];
            int slot = atomicAdd(&cnt[r], 1);
            if (slot < CAP) {
                adjc[(size_t)r * CAP + slot] = col;
                float em = emask[e];
                float2 de; de.x = dist[e] * em; de.y = em;
                dm[(size_t)r * CAP + slot] = de;
            }
        }
    }
}

// ------- prc_kernel: per-node layer-1 projections -------
// prf[n][o] = sum_k x[n][k] W1[o][k] + b1[o]   (f32, bias folded)
// pcb[n][o] = sum_k x[n][k] W1[o][128+k]       (bf16)
#define PRC_NPB 16
__global__ __launch_bounds__(256) void prc_kernel(
    const unsigned short* __restrict__ xb,
    const unsigned short* __restrict__ w1b,
    const float* __restrict__ b1,
    float* __restrict__ prf, unsigned short* __restrict__ pcb) {
    int n0 = blockIdx.x * PRC_NPB;
    int w = threadIdx.x >> 6, lane = threadIdx.x & 63;
    int lrow = lane & 15, quad = lane >> 4;

    bf16x8 a[4];
#pragma unroll
    for (int kk = 0; kk < 4; ++kk)
        a[kk] = *(const bf16x8*)&xb[(size_t)(n0 + lrow) * DIM + kk * 32 + quad * 8];

    f32x4 z = {0.f, 0.f, 0.f, 0.f};
#pragma unroll
    for (int i = 0; i < 8; ++i) {
        int gt = w * 8 + i;
        int half = gt >> 4;            // 0 -> prf, 1 -> pcb
        int obase = (gt & 15) * 16;
        f32x4 acc = z;
#pragma unroll
        for (int kk = 0; kk < 4; ++kk) {
            bf16x8 bfrag = *(const bf16x8*)&w1b[(size_t)(obase + lrow) * 256 + half * 128 + kk * 32 + quad * 8];
            acc = __builtin_amdgcn_mfma_f32_16x16x32_bf16(a[kk], bfrag, acc, 0, 0, 0);
        }
        int o = obase + lrow;
        if (half == 0) {
            float bias = b1[o];
#pragma unroll
            for (int r = 0; r < 4; ++r)
                prf[(size_t)(n0 + quad * 4 + r) * 256 + o] = acc[r] + bias;
        } else {
#pragma unroll
            for (int r = 0; r < 4; ++r)
                pcb[(size_t)(n0 + quad * 4 + r) * 256 + o] = f2bf(acc[r]);
        }
    }
}

// ---------------- Kernel 3: edge MLP in adj-order -> attA[N*CAP] ----------------
// Block = 8 nodes' adjacency lists. pr rows (f32, bias folded) are L1-hot
// (8 x 1KB per block); pc is the single remaining random bf16 stream.
// att written in adj-order (coalesced consume in node_kernel).
__global__ __launch_bounds__(512, 4) void edge_kernel(
    const float* __restrict__ prf, const unsigned short* __restrict__ pcb,
    const float2* __restrict__ dm, const int* __restrict__ adjc,
    const int* __restrict__ cnt,
    const float* __restrict__ w1p,
    const unsigned short* __restrict__ w2b, const float* __restrict__ b2,
    const float* __restrict__ w3, const float* __restrict__ b3v,
    float* __restrict__ attA) {
    __shared__ unsigned short buf[EPB * XST];
    __shared__ float part[8][EPB];
    __shared__ float w1ps[256];
    __shared__ unsigned short list[NPB * CAP];
    __shared__ int offs[NPB + 1];
    __shared__ int cnts[NPB];
    __shared__ int cidx_s[EPB], jj_s[EPB];
    __shared__ float dv_s[EPB], em_s[EPB];

    int tid = threadIdx.x;
    int n0 = blockIdx.x * NPB;

    if (tid < NPB) { int c = cnt[n0 + tid]; cnts[tid] = c > CAP ? CAP : c; }
    if (tid >= 256 && tid < 512) w1ps[tid - 256] = w1p[tid - 256];
    __syncthreads();
    if (tid == 0) {
        int s = 0;
#pragma unroll
        for (int j = 0; j < NPB; ++j) { offs[j] = s; s += cnts[j]; }
        offs[NPB] = s;
    }
    __syncthreads();
    {
        int jg = tid >> 5, l = tid & 31;
        if (jg < NPB) {
            int c = cnts[jg], o = offs[jg];
            for (int i = l; i < c; i += 32) list[o + i] = (unsigned short)((jg << 8) | i);
        }
    }
    int count = offs[NPB];
    int ntiles = (count + EPB - 1) / EPB;
    __syncthreads();

    int wave = tid >> 6, lane = tid & 63;
    int lrow = lane & 15, quad = lane >> 4;
    int n2 = wave * 16 + lrow;
    float bias2 = b2[n2];
    float w3v = w3[n2];
    float b3s = b3v[0];

    f32x4 zz = {0.f, 0.f, 0.f, 0.f};

    for (int t = 0; t < ntiles; ++t) {
        // ---- stage tile edge info
        if (tid < EPB) {
            int s = t * EPB + tid;
            if (s < count) {
                int ji = list[s];
                int j = ji >> 8, i = ji & 255;
                size_t ai = (size_t)(n0 + j) * CAP + i;
                float2 de = dm[ai];
                jj_s[tid] = j; cidx_s[tid] = adjc[ai];
                dv_s[tid] = de.x; em_s[tid] = de.y;
            } else {
                jj_s[tid] = 0; cidx_s[tid] = 0;
                dv_s[tid] = 0.f; em_s[tid] = 0.f;
            }
        }
        __syncthreads();

        // ---- gather + layer-1 epilogue: thread (ge = tid>>3, cb = tid&7)
        // owns one 32-neuron chunk of one edge; pairs (o, o+16) pack to
        // permuted position matching w2b's k-order.
        {
            int ge = tid >> 3, cb = tid & 7;
            const unsigned short* pcp = pcb + (size_t)cidx_s[ge] * 256 + cb * 32;
            const float* prow = prf + (size_t)(n0 + jj_s[ge]) * 256 + cb * 32;
            float d = dv_s[ge];
            unsigned* wrow = (unsigned*)&buf[ge * XST + cb * 32];
            const float* wp = &w1ps[cb * 32];

            float pa[8], pb[8];
            *(float4*)&pa[0] = *(const float4*)&prow[0];
            *(float4*)&pa[4] = *(const float4*)&prow[4];
            *(float4*)&pb[0] = *(const float4*)&prow[16];
            *(float4*)&pb[4] = *(const float4*)&prow[20];
            bf16x8 qA = *(const bf16x8*)&pcp[0];
            bf16x8 qB = *(const bf16x8*)&pcp[16];
#pragma unroll
            for (int l = 0; l < 8; ++l) {
                float s0 = pa[l] + bf2f((unsigned short)qA[l]) + d * wp[2 * l];
                float s1 = pb[l] + bf2f((unsigned short)qB[l]) + d * wp[2 * l + 1];
                wrow[l] = pack_bf16(fsilu(s0), fsilu(s1));
            }
            *(float4*)&pa[0] = *(const float4*)&prow[8];
            *(float4*)&pa[4] = *(const float4*)&prow[12];
            *(float4*)&pb[0] = *(const float4*)&prow[24];
            *(float4*)&pb[4] = *(const float4*)&prow[28];
            qA = *(const bf16x8*)&pcp[8];
            qB = *(const bf16x8*)&pcp[24];
#pragma unroll
            for (int l = 0; l < 8; ++l) {
                float s0 = pa[l] + bf2f((unsigned short)qA[l]) + d * wp[16 + 2 * l];
                float s1 = pb[l] + bf2f((unsigned short)qB[l]) + d * wp[16 + 2 * l + 1];
                wrow[8 + l] = pack_bf16(fsilu(s0), fsilu(s1));
            }
        }
        __syncthreads();

        // ---- layer 2: wave covers 16 of 128 N2 (k-order permuted on both sides)
        f32x4 acc2[4];
#pragma unroll
        for (int mt = 0; mt < 4; ++mt) acc2[mt] = zz;

        for (int kk = 0; kk < 8; ++kk) {
            int ka = kk * 32 + quad * 8;
            bf16x8 bfrag = *(const bf16x8*)&w2b[(size_t)n2 * 256 + ka];
#pragma unroll
            for (int mt = 0; mt < 4; ++mt) {
                bf16x8 a = *(bf16x8*)&buf[(mt * 16 + lrow) * XST + ka];
                acc2[mt] = __builtin_amdgcn_mfma_f32_16x16x32_bf16(a, bfrag, acc2[mt], 0, 0, 0);
            }
        }

        // ---- layer 3 in registers
        float s[4][4];
#pragma unroll
        for (int mt = 0; mt < 4; ++mt)
#pragma unroll
            for (int r = 0; r < 4; ++r)
                s[mt][r] = fsilu(acc2[mt][r] + bias2) * w3v;
#pragma unroll
        for (int off = 1; off < 16; off <<= 1) {
#pragma unroll
            for (int mt = 0; mt < 4; ++mt)
#pragma unroll
                for (int r = 0; r < 4; ++r)
                    s[mt][r] += __shfl_xor(s[mt][r], off);
        }
        if (lrow == 0) {
#pragma unroll
            for (int mt = 0; mt < 4; ++mt)
#pragma unroll
                for (int r = 0; r < 4; ++r)
                    part[wave][mt * 16 + quad * 4 + r] = s[mt][r];
        }
        __syncthreads();

        if (tid < EPB) {
            int sidx = t * EPB + tid;
            if (sidx < count) {
                float ssum = b3s;
#pragma unroll
                for (int w = 0; w < 8; ++w) ssum += part[w][tid];
                int ji = list[sidx];
                int j = ji >> 8, i = ji & 255;
                attA[(size_t)(n0 + j) * CAP + i] = fsig(ssum) * em_s[tid];
            }
        }
        // no extra sync needed: next tile's writers cross >=2 barriers first
    }
}

// ---------------- Kernel 4: aggregate + node MLP + LNs ----------------
__global__ __launch_bounds__(256) void node_kernel(
    const float* __restrict__ attA, const int* __restrict__ adjc, const int* __restrict__ cnt,
    const unsigned short* __restrict__ xb,
    const float* __restrict__ x,
    const float* __restrict__ w1, const float* __restrict__ bb1,
    const float* __restrict__ lng, const float* __restrict__ lnb,
    const float* __restrict__ w2, const float* __restrict__ bb2,
    const float* __restrict__ gF, const float* __restrict__ bF,
    float* __restrict__ out, int E) {
    __shared__ float atts[NPB][CAP];
    __shared__ int   cols[NPB][CAP];
    __shared__ float outv[NPB][128];
    __shared__ float bufs[NPB][128];
    __shared__ float mu_s[NPB], rs_s[NPB];
    __shared__ int cnts[NPB];

    int t = threadIdx.x;
    int n0 = blockIdx.x * NPB;

    if (t < NPB) { int c = cnt[n0 + t]; cnts[t] = c > CAP ? CAP : c; }
    __syncthreads();

    {
        int jg = t >> 5, l = t & 31;
        int c = cnts[jg];
        const int* al = adjc + (size_t)(n0 + jg) * CAP;
        const float* av = attA + (size_t)(n0 + jg) * CAP;
        for (int i = l; i < c; i += 32) {
            atts[jg][i] = av[i];
            cols[jg][i] = al[i];
        }
    }
    __syncthreads();

    int w = t >> 6, lane = t & 63;
#pragma unroll
    for (int jj = 0; jj < 2; ++jj) {
        int j = w * 2 + jj;
        int c = cnts[j];
        float lo0 = 0.f, hi0 = 0.f, lo1 = 0.f, hi1 = 0.f;
        float lo2 = 0.f, hi2 = 0.f, lo3 = 0.f, hi3 = 0.f;
        int i = 0;
        for (; i + 3 < c; i += 4) {
            unsigned u0 = *(const unsigned*)&xb[(size_t)cols[j][i]     * DIM + lane * 2];
            unsigned u1 = *(const unsigned*)&xb[(size_t)cols[j][i + 1] * DIM + lane * 2];
            unsigned u2 = *(const unsigned*)&xb[(size_t)cols[j][i + 2] * DIM + lane * 2];
            unsigned u3 = *(const unsigned*)&xb[(size_t)cols[j][i + 3] * DIM + lane * 2];
            float w0 = atts[j][i], w1v = atts[j][i + 1], w2v = atts[j][i + 2], w3v = atts[j][i + 3];
            lo0 += w0 * bf2f((unsigned short)(u0 & 0xffff)); hi0 += w0 * bf2f((unsigned short)(u0 >> 16));
            lo1 += w1v * bf2f((unsigned short)(u1 & 0xffff)); hi1 += w1v * bf2f((unsigned short)(u1 >> 16));
            lo2 += w2v * bf2f((unsigned short)(u2 & 0xffff)); hi2 += w2v * bf2f((unsigned short)(u2 >> 16));
            lo3 += w3v * bf2f((unsigned short)(u3 & 0xffff)); hi3 += w3v * bf2f((unsigned short)(u3 >> 16));
        }
        for (; i < c; ++i) {
            unsigned u0 = *(const unsigned*)&xb[(size_t)cols[j][i] * DIM + lane * 2];
            float w0 = atts[j][i];
            lo0 += w0 * bf2f((unsigned short)(u0 & 0xffff));
            hi0 += w0 * bf2f((unsigned short)(u0 >> 16));
        }
        outv[j][lane * 2]     = ((lo0 + lo1) + (lo2 + lo3)) * 0.01f;
        outv[j][lane * 2 + 1] = ((hi0 + hi1) + (hi2 + hi3)) * 0.01f;
    }
    __syncthreads();

    int h = t >> 7, ch = t & 127;
    float xres[4];
#pragma unroll
    for (int jj = 0; jj < 4; ++jj)
        xres[jj] = x[(size_t)(n0 + h * 4 + jj) * DIM + ch];

    float a1[4] = {0, 0, 0, 0};
    for (int kc = 0; kc < 128; kc += 4) {
        float4 wv = *(const float4*)&w1[(size_t)ch * DIM + kc];
#pragma unroll
        for (int jj = 0; jj < 4; ++jj) {
            int j = h * 4 + jj;
            a1[jj] += wv.x * outv[j][kc] + wv.y * outv[j][kc + 1] + wv.z * outv[j][kc + 2] + wv.w * outv[j][kc + 3];
        }
    }
    float bias1 = bb1[ch];
#pragma unroll
    for (int jj = 0; jj < 4; ++jj) bufs[h * 4 + jj][ch] = a1[jj] + bias1;
    __syncthreads();

    {
        int j = t >> 5, l = t & 31;
        float s = 0.f, qq = 0.f;
#pragma unroll
        for (int i = 0; i < 4; ++i) { float v = bufs[j][l + 32 * i]; s += v; qq += v * v; }
#pragma unroll
        for (int off = 16; off; off >>= 1) { s += __shfl_xor(s, off); qq += __shfl_xor(qq, off); }
        if (l == 0) {
            float mu = s * (1.f / 128.f);
            float var = qq * (1.f / 128.f) - mu * mu;
            mu_s[j] = mu; rs_s[j] = __builtin_amdgcn_rsqf(var + 1e-5f);
        }
    }
    __syncthreads();

    float g = lng[ch], bb = lnb[ch];
    float h2[4];
#pragma unroll
    for (int jj = 0; jj < 4; ++jj) {
        int j = h * 4 + jj;
        h2[jj] = fsilu((bufs[j][ch] - mu_s[j]) * rs_s[j] * g + bb);
    }
    __syncthreads();
#pragma unroll
    for (int jj = 0; jj < 4; ++jj) bufs[h * 4 + jj][ch] = h2[jj];
    __syncthreads();

    float a3[4] = {0, 0, 0, 0};
    for (int kc = 0; kc < 128; kc += 4) {
        float4 wv = *(const float4*)&w2[(size_t)ch * DIM + kc];
#pragma unroll
        for (int jj = 0; jj < 4; ++jj) {
            int j = h * 4 + jj;
            a3[jj] += wv.x * bufs[j][kc] + wv.y * bufs[j][kc + 1] + wv.z * bufs[j][kc + 2] + wv.w * bufs[j][kc + 3];
        }
    }
    float bias2 = bb2[ch];
    float hh[4];
#pragma unroll
    for (int jj = 0; jj < 4; ++jj) hh[jj] = a3[jj] + bias2 + xres[jj];
    __syncthreads();
#pragma unroll
    for (int jj = 0; jj < 4; ++jj) bufs[h * 4 + jj][ch] = hh[jj];
    __syncthreads();

    {
        int j = t >> 5, l = t & 31;
        float s = 0.f, qq = 0.f;
#pragma unroll
        for (int i = 0; i < 4; ++i) { float v = bufs[j][l + 32 * i]; s += v; qq += v * v; }
#pragma unroll
        for (int off = 16; off; off >>= 1) { s += __shfl_xor(s, off); qq += __shfl_xor(qq, off); }
        if (l == 0) {
            float mu = s * (1.f / 128.f);
            float var = qq * (1.f / 128.f) - mu * mu;
            mu_s[j] = mu; rs_s[j] = __builtin_amdgcn_rsqf(var + 1e-5f);
        }
    }
    __syncthreads();

    float gf = gF[ch], bf = bF[ch];
#pragma unroll
    for (int jj = 0; jj < 4; ++jj) {
        int j = h * 4 + jj;
        float y = (hh[jj] - mu_s[j]) * rs_s[j] * gf + bf;
        out[(size_t)(n0 + j) * DIM + ch] = fsilu(y);
    }
}

extern "C" void kernel_launch(void* const* d_in, const int* in_sizes, int n_in,
                              void* d_out, int out_size, void* d_ws, size_t ws_size,
                              hipStream_t stream) {
    const float* h         = (const float*)d_in[0];
    const float* distances = (const float*)d_in[1];
    const float* edge_mask = (const float*)d_in[3];
    const float* lin_w     = (const float*)d_in[4];
    const float* lin_b     = (const float*)d_in[5];
    const float* att_w1    = (const float*)d_in[6];
    const float* att_b1    = (const float*)d_in[7];
    const float* att_w2    = (const float*)d_in[8];
    const float* att_b2    = (const float*)d_in[9];
    const float* att_w3    = (const float*)d_in[10];
    const float* att_b3    = (const float*)d_in[11];
    const float* nm_w1     = (const float*)d_in[12];
    const float* nm_b1     = (const float*)d_in[13];
    const float* nm_ln_g   = (const float*)d_in[14];
    const float* nm_ln_b   = (const float*)d_in[15];
    const float* nm_w2     = (const float*)d_in[16];
    const float* nm_b2     = (const float*)d_in[17];
    const float* ln_g      = (const float*)d_in[18];
    const float* ln_b      = (const float*)d_in[19];
    const int*   edges     = (const int*)d_in[20];
    float* out = (float*)d_out;

    const int N = N_NODES, E = E_EDGES;

    char* ws = (char*)d_ws;
    float* x            = (float*)ws;            ws += (size_t)N * DIM * 4;
    unsigned short* xb  = (unsigned short*)ws;   ws += (size_t)N * DIM * 2;
    int* cnt            = (int*)ws;              ws += (size_t)N * 4;
    int* adjc           = (int*)ws;              ws += (size_t)N * CAP * 4;
    float2* dm          = (float2*)ws;           ws += (size_t)N * CAP * 8;
    float* attA         = (float*)ws;            ws += (size_t)N * CAP * 4;
    unsigned short* w1b = (unsigned short*)ws;   ws += 256 * 256 * 2;
    float* w1p          = (float*)ws;            ws += 256 * 4;
    unsigned short* w2b = (unsigned short*)ws;   ws += 128 * 256 * 2;
    float* prf          = (float*)ws;            ws += (size_t)N * 256 * 4;
    unsigned short* pcb = (unsigned short*)ws;   ws += (size_t)N * 256 * 2;

    hipMemsetAsync(cnt, 0, (size_t)N * 4, stream);

    pre_kernel<<<PRE_PREP_BLOCKS + PRE_LIN_BLOCKS + PRE_ADJ_BLOCKS, 256, 0, stream>>>(
        att_w1, att_w2, w1b, w1p, w2b,
        h, lin_w, lin_b, x, xb,
        edges, distances, edge_mask, cnt, adjc, dm, E);
    prc_kernel<<<N / PRC_NPB, 256, 0, stream>>>(xb, w1b, att_b1, prf, pcb);
    edge_kernel<<<N / NPB, 512, 0, stream>>>(prf, pcb, dm, adjc, cnt,
                                             w1p, w2b, att_b2,
                                             att_w3, att_b3, attA);
    node_kernel<<<N / NPB, 256, 0, stream>>>(attA, adjc, cnt, xb, x,
                                             nm_w1, nm_b1, nm_ln_g, nm_ln_b,
                                             nm_w2, nm_b2, ln_g, ln_b, out, E);
}

// Round 3
// 461.399 us; speedup vs baseline: 1.0379x; 1.0379x over previous
//
#include <hip/hip_runtime.h>
#include <hip/hip_bf16.h>

#define N_NODES 20000
#define E_EDGES 640000
#define DIM 128
#define CAP 96    // Poisson(32) max degree ~65; 96 is >10-sigma safe
#define EPB 64    // edges per block in edge_kernel
#define NPB 8     // nodes per block in node_kernel / flat build
#define XST 264   // padded ushort stride for [64][256] LDS tile

typedef __attribute__((ext_vector_type(8))) short bf16x8;
typedef __attribute__((ext_vector_type(4))) float f32x4;

#define LOG2E 1.44269504f
__device__ __forceinline__ float fsilu(float x) {
    return x * __builtin_amdgcn_rcpf(1.f + __builtin_amdgcn_exp2f(-LOG2E * x));
}
__device__ __forceinline__ float fsig(float x) {
    return __builtin_amdgcn_rcpf(1.f + __builtin_amdgcn_exp2f(-LOG2E * x));
}

__device__ __forceinline__ unsigned short f2bf(float x) {
    union { float f; unsigned u; } v; v.f = x;
    unsigned r = (v.u + 0x7fffu + ((v.u >> 16) & 1u)) >> 16;
    return (unsigned short)r;
}
__device__ __forceinline__ float bf2f(unsigned short s) {
    union { unsigned u; float f; } v; v.u = ((unsigned)s) << 16;
    return v.f;
}
// pack two floats to packed bf16 {lo,hi} with round-half-up
__device__ __forceinline__ unsigned pack_bf16(float lo, float hi) {
    union { float f; unsigned u; } a, b; a.f = lo; b.f = hi;
    unsigned ul = a.u + 0x8000u, uh = b.u + 0x8000u;
    return __builtin_amdgcn_perm(uh, ul, 0x07060302u);
}

// ------- fused pre-kernel: weight prep (64) + lin (625) + adj build (2500) -------
#define PRE_PREP_BLOCKS 64
#define PRE_LIN_BLOCKS  625   // 32 nodes per block
#define PRE_ADJ_BLOCKS  2500
__global__ __launch_bounds__(256) void pre_kernel(
    const float* __restrict__ w1, const float* __restrict__ w2,
    unsigned short* __restrict__ w1b, float* __restrict__ w1p,
    unsigned short* __restrict__ w2b,
    const float* __restrict__ h, const float* __restrict__ lw,
    const float* __restrict__ lb, float* __restrict__ x,
    unsigned short* __restrict__ xb,
    const int* __restrict__ edges, int* __restrict__ cnt,
    int2* __restrict__ adj2, int E) {
    __shared__ float hs[32][128];
    int b = blockIdx.x;
    int t = threadIdx.x;

    if (b < PRE_PREP_BLOCKS) {
        int i = b * 256 + t;
        const int stride = PRE_PREP_BLOCKS * 256;
        for (int idx = i; idx < 256 * 256; idx += stride) {
            int o = idx >> 8, k = idx & 255;
            w1b[idx] = f2bf(w1[o * 257 + k]);
        }
        // w2b k-order permuted: within each 32-chunk b2: pos b2+2l <- k=b2+l ; b2+2l+1 <- k=b2+16+l
        for (int idx = i; idx < 128 * 256; idx += stride) {
            int n2 = idx >> 8, p = idx & 255;
            int bb = p & ~31, off = p & 31;
            int ksrc = bb + (off >> 1) + ((off & 1) << 4);
            w2b[idx] = f2bf(w2[n2 * 256 + ksrc]);
        }
        // w1last in the SAME permuted order as the a1 LDS tile / w2b k-order
        for (int idx = i; idx < 256; idx += stride) {
            int bb = idx & ~31, off = idx & 31;
            int ksrc = bb + (off >> 1) + ((off & 1) << 4);
            w1p[idx] = w1[ksrc * 257 + 256];
        }
    } else if (b < PRE_PREP_BLOCKS + PRE_LIN_BLOCKS) {
        int nb = b - PRE_PREP_BLOCKS;
        int n0 = nb * 32;
        int ch = t & 127, g = t >> 7;   // g in {0,1}, 16 nodes each
#pragma unroll
        for (int j = 0; j < 16; ++j) hs[g * 16 + j][ch] = h[(size_t)(n0 + g * 16 + j) * DIM + ch];
        __syncthreads();
        float acc[16];
#pragma unroll
        for (int j = 0; j < 16; ++j) acc[j] = 0.f;
        for (int kc = 0; kc < 128; kc += 4) {
            float4 wv = *(const float4*)&lw[(size_t)ch * DIM + kc];
#pragma unroll
            for (int j = 0; j < 16; ++j)
                acc[j] += wv.x * hs[g * 16 + j][kc] + wv.y * hs[g * 16 + j][kc + 1]
                        + wv.z * hs[g * 16 + j][kc + 2] + wv.w * hs[g * 16 + j][kc + 3];
        }
        float bias = lb[ch];
#pragma unroll
        for (int j = 0; j < 16; ++j) {
            float v = acc[j] + bias;
            int n = n0 + g * 16 + j;
            x[(size_t)n * DIM + ch] = v;
            xb[(size_t)n * DIM + ch] = f2bf(v);
        }
    } else {
        int e = (b - PRE_PREP_BLOCKS - PRE_LIN_BLOCKS) * 256 + t;
        if (e < E) {
            int r = edges[e];
            int col = edges[E + e];
            int slot = atomicAdd(&cnt[r], 1);
            if (slot < CAP) { int2 v; v.x = e; v.y = col; adj2[(size_t)r * CAP + slot] = v; }
        }
    }
}

// ------- scan_kernel: exclusive prefix sum of clamped cnt -> off[N+1] -------
__global__ __launch_bounds__(1024) void scan_kernel(const int* __restrict__ cnt,
                                                    int* __restrict__ off) {
    __shared__ int part[1024];
    int t = threadIdx.x;
    int base = t * 20;
    int loc[20];
    int s = 0;
#pragma unroll
    for (int i = 0; i < 20; ++i) {
        int idx = base + i;
        int v = 0;
        if (idx < N_NODES) { v = cnt[idx]; v = v > CAP ? CAP : v; }
        loc[i] = s; s += v;
    }
    part[t] = s;
    __syncthreads();
    int run = s;
    for (int d = 1; d < 1024; d <<= 1) {
        int v = (t >= d) ? part[t - d] : 0;
        __syncthreads();
        part[t] += v;
        __syncthreads();
    }
    int ex = part[t] - run;
#pragma unroll
    for (int i = 0; i < 20; ++i) {
        int idx = base + i;
        if (idx < N_NODES) off[idx] = ex + loc[i];
    }
    if (t == 1023) off[N_NODES] = part[1023];
}

// ------- mid_kernel: prc (1250 blocks) + flat edge-list build (2500 blocks) -------
// prc: prf[n][o] = x@W1r^T + b1 (f32); pcb[n][o] = x@W1c^T (bf16)
// flat: adj-ordered int4 {row, col, bits(d*em), bits(em)}
#define MID_PRC_BLOCKS 1250    // N/16
#define MID_FLAT_BLOCKS 2500   // N/8
__global__ __launch_bounds__(256) void mid_kernel(
    const unsigned short* __restrict__ xb,
    const unsigned short* __restrict__ w1b,
    const float* __restrict__ b1,
    float* __restrict__ prf, unsigned short* __restrict__ pcb,
    const int2* __restrict__ adj2, const int* __restrict__ cnt,
    const int* __restrict__ off,
    const float* __restrict__ dist, const float* __restrict__ emask,
    int4* __restrict__ flat) {
    int b = blockIdx.x;
    if (b < MID_PRC_BLOCKS) {
        int n0 = b * 16;
        int w = threadIdx.x >> 6, lane = threadIdx.x & 63;
        int lrow = lane & 15, quad = lane >> 4;

        bf16x8 a[4];
#pragma unroll
        for (int kk = 0; kk < 4; ++kk)
            a[kk] = *(const bf16x8*)&xb[(size_t)(n0 + lrow) * DIM + kk * 32 + quad * 8];

        f32x4 z = {0.f, 0.f, 0.f, 0.f};
#pragma unroll
        for (int i = 0; i < 8; ++i) {
            int gt = w * 8 + i;
            int half = gt >> 4;            // 0 -> prf, 1 -> pcb
            int obase = (gt & 15) * 16;
            f32x4 acc = z;
#pragma unroll
            for (int kk = 0; kk < 4; ++kk) {
                bf16x8 bfrag = *(const bf16x8*)&w1b[(size_t)(obase + lrow) * 256 + half * 128 + kk * 32 + quad * 8];
                acc = __builtin_amdgcn_mfma_f32_16x16x32_bf16(a[kk], bfrag, acc, 0, 0, 0);
            }
            int o = obase + lrow;
            if (half == 0) {
                float bias = b1[o];
#pragma unroll
                for (int r = 0; r < 4; ++r)
                    prf[(size_t)(n0 + quad * 4 + r) * 256 + o] = acc[r] + bias;
            } else {
#pragma unroll
                for (int r = 0; r < 4; ++r)
                    pcb[(size_t)(n0 + quad * 4 + r) * 256 + o] = f2bf(acc[r]);
            }
        }
    } else {
        int fb = b - MID_PRC_BLOCKS;
        int n0 = fb * NPB;
        int jg = threadIdx.x >> 5, l = threadIdx.x & 31;
        int n = n0 + jg;
        int c = cnt[n]; c = c > CAP ? CAP : c;
        int o = off[n];
        const int2* al = adj2 + (size_t)n * CAP;
        for (int i = l; i < c; i += 32) {
            int2 v = al[i];
            float em = emask[v.x];
            float dv = dist[v.x] * em;
            int4 wv;
            union { float f; int i; } u1, u2; u1.f = dv; u2.f = em;
            wv.x = n; wv.y = v.y; wv.z = u1.i; wv.w = u2.i;
            flat[o + i] = wv;
        }
    }
}

// ---------------- Kernel 4: edge MLP over flat adj-ordered list ----------------
// R1 structure (10000 independent blocks, one 64-edge tile each), but rows
// arrive grouped: prf[row] reads are L1-hot (~2-3 distinct rows/block).
// pcb[col] is the single remaining random stream. att written flat-ordered.
__global__ __launch_bounds__(512, 4) void edge_kernel(
    const float* __restrict__ prf, const unsigned short* __restrict__ pcb,
    const int4* __restrict__ flat, const int* __restrict__ off,
    const float* __restrict__ w1p,
    const unsigned short* __restrict__ w2b, const float* __restrict__ b2,
    const float* __restrict__ w3, const float* __restrict__ b3v,
    float* __restrict__ attv) {
    __shared__ unsigned short buf[EPB * XST];
    __shared__ float part[8][EPB];
    __shared__ float w1ps[256];
    __shared__ float dvals[EPB], emv[EPB];
    __shared__ int ridx[EPB], cidx[EPB];

    int tid = threadIdx.x;
    int eb = blockIdx.x * EPB;

    if (tid < EPB) {
        int count = off[N_NODES];
        int idx = eb + tid;
        int4 v;
        if (idx < count) v = flat[idx];
        else { v.x = 0; v.y = 0; v.z = 0; v.w = 0; }
        ridx[tid] = v.x; cidx[tid] = v.y;
        union { int i; float f; } a, bu; a.i = v.z; bu.i = v.w;
        dvals[tid] = a.f; emv[tid] = bu.f;
    }
    if (tid >= 64 && tid < 320) w1ps[tid - 64] = w1p[tid - 64];

    int wave = tid >> 6, lane = tid & 63;
    int lrow = lane & 15, quad = lane >> 4;
    int n2 = wave * 16 + lrow;
    float bias2 = b2[n2];
    float w3v = w3[n2];

    __syncthreads();

    // ---- gather + layer-1 epilogue: thread (ge = tid>>3, cb = tid&7) owns one
    // 32-neuron chunk of one edge. Pairs (o, o+16) pack to the permuted
    // position matching w2b's k-order.
    {
        int ge = tid >> 3, cb = tid & 7;
        const float* prow = prf + (size_t)ridx[ge] * 256 + cb * 32;
        const unsigned short* pcp = pcb + (size_t)cidx[ge] * 256 + cb * 32;
        float d = dvals[ge];
        unsigned* wrow = (unsigned*)&buf[ge * XST + cb * 32];
        const float* wp = &w1ps[cb * 32];

        float pa[8], pb[8];
        *(float4*)&pa[0] = *(const float4*)&prow[0];
        *(float4*)&pa[4] = *(const float4*)&prow[4];
        *(float4*)&pb[0] = *(const float4*)&prow[16];
        *(float4*)&pb[4] = *(const float4*)&prow[20];
        bf16x8 qA = *(const bf16x8*)&pcp[0];
        bf16x8 qB = *(const bf16x8*)&pcp[16];
#pragma unroll
        for (int l = 0; l < 8; ++l) {
            float s0 = pa[l] + bf2f((unsigned short)qA[l]) + d * wp[2 * l];
            float s1 = pb[l] + bf2f((unsigned short)qB[l]) + d * wp[2 * l + 1];
            wrow[l] = pack_bf16(fsilu(s0), fsilu(s1));
        }
        *(float4*)&pa[0] = *(const float4*)&prow[8];
        *(float4*)&pa[4] = *(const float4*)&prow[12];
        *(float4*)&pb[0] = *(const float4*)&prow[24];
        *(float4*)&pb[4] = *(const float4*)&prow[28];
        qA = *(const bf16x8*)&pcp[8];
        qB = *(const bf16x8*)&pcp[24];
#pragma unroll
        for (int l = 0; l < 8; ++l) {
            float s0 = pa[l] + bf2f((unsigned short)qA[l]) + d * wp[16 + 2 * l];
            float s1 = pb[l] + bf2f((unsigned short)qB[l]) + d * wp[16 + 2 * l + 1];
            wrow[8 + l] = pack_bf16(fsilu(s0), fsilu(s1));
        }
    }
    __syncthreads();

    // ---- layer 2: wave covers 16 of 128 N2 (k-order permuted on both sides)
    f32x4 zz = {0.f, 0.f, 0.f, 0.f};
    f32x4 acc2[4];
#pragma unroll
    for (int mt = 0; mt < 4; ++mt) acc2[mt] = zz;

    for (int kk = 0; kk < 8; ++kk) {
        int ka = kk * 32 + quad * 8;
        bf16x8 bfrag = *(const bf16x8*)&w2b[(size_t)n2 * 256 + ka];
#pragma unroll
        for (int mt = 0; mt < 4; ++mt) {
            bf16x8 a = *(bf16x8*)&buf[(mt * 16 + lrow) * XST + ka];
            acc2[mt] = __builtin_amdgcn_mfma_f32_16x16x32_bf16(a, bfrag, acc2[mt], 0, 0, 0);
        }
    }

    // ---- layer 3 in registers
    float s[4][4];
#pragma unroll
    for (int mt = 0; mt < 4; ++mt)
#pragma unroll
        for (int r = 0; r < 4; ++r)
            s[mt][r] = fsilu(acc2[mt][r] + bias2) * w3v;
#pragma unroll
    for (int off2 = 1; off2 < 16; off2 <<= 1) {
#pragma unroll
        for (int mt = 0; mt < 4; ++mt)
#pragma unroll
            for (int r = 0; r < 4; ++r)
                s[mt][r] += __shfl_xor(s[mt][r], off2);
    }
    if (lrow == 0) {
#pragma unroll
        for (int mt = 0; mt < 4; ++mt)
#pragma unroll
            for (int r = 0; r < 4; ++r)
                part[wave][mt * 16 + quad * 4 + r] = s[mt][r];
    }
    __syncthreads();

    if (tid < EPB) {
        float ssum = b3v[0];
#pragma unroll
        for (int w = 0; w < 8; ++w) ssum += part[w][tid];
        attv[eb + tid] = fsig(ssum) * emv[tid];
    }
}

// ---------------- Kernel 5: aggregate + node MLP + LNs ----------------
__global__ __launch_bounds__(256) void node_kernel(
    const float* __restrict__ attv, const int2* __restrict__ adj2,
    const int* __restrict__ cnt, const int* __restrict__ off,
    const unsigned short* __restrict__ xb,
    const float* __restrict__ x,
    const float* __restrict__ w1, const float* __restrict__ bb1,
    const float* __restrict__ lng, const float* __restrict__ lnb,
    const float* __restrict__ w2, const float* __restrict__ bb2,
    const float* __restrict__ gF, const float* __restrict__ bF,
    float* __restrict__ out, int E) {
    __shared__ float atts[NPB][CAP];
    __shared__ int   cols[NPB][CAP];
    __shared__ float outv[NPB][128];
    __shared__ float bufs[NPB][128];
    __shared__ float mu_s[NPB], rs_s[NPB];
    __shared__ int cnts[NPB];

    int t = threadIdx.x;
    int n0 = blockIdx.x * NPB;

    if (t < NPB) { int c = cnt[n0 + t]; cnts[t] = c > CAP ? CAP : c; }
    __syncthreads();

    {
        int jg = t >> 5, l = t & 31;
        int c = cnts[jg];
        const int2* al = adj2 + (size_t)(n0 + jg) * CAP;
        const float* av = attv + off[n0 + jg];
        for (int i = l; i < c; i += 32) {
            atts[jg][i] = av[i];
            cols[jg][i] = al[i].y;
        }
    }
    __syncthreads();

    int w = t >> 6, lane = t & 63;
#pragma unroll
    for (int jj = 0; jj < 2; ++jj) {
        int j = w * 2 + jj;
        int c = cnts[j];
        float lo0 = 0.f, hi0 = 0.f, lo1 = 0.f, hi1 = 0.f;
        float lo2 = 0.f, hi2 = 0.f, lo3 = 0.f, hi3 = 0.f;
        int i = 0;
        for (; i + 3 < c; i += 4) {
            unsigned u0 = *(const unsigned*)&xb[(size_t)cols[j][i]     * DIM + lane * 2];
            unsigned u1 = *(const unsigned*)&xb[(size_t)cols[j][i + 1] * DIM + lane * 2];
            unsigned u2 = *(const unsigned*)&xb[(size_t)cols[j][i + 2] * DIM + lane * 2];
            unsigned u3 = *(const unsigned*)&xb[(size_t)cols[j][i + 3] * DIM + lane * 2];
            float w0 = atts[j][i], w1v = atts[j][i + 1], w2v = atts[j][i + 2], w3v = atts[j][i + 3];
            lo0 += w0 * bf2f((unsigned short)(u0 & 0xffff)); hi0 += w0 * bf2f((unsigned short)(u0 >> 16));
            lo1 += w1v * bf2f((unsigned short)(u1 & 0xffff)); hi1 += w1v * bf2f((unsigned short)(u1 >> 16));
            lo2 += w2v * bf2f((unsigned short)(u2 & 0xffff)); hi2 += w2v * bf2f((unsigned short)(u2 >> 16));
            lo3 += w3v * bf2f((unsigned short)(u3 & 0xffff)); hi3 += w3v * bf2f((unsigned short)(u3 >> 16));
        }
        for (; i < c; ++i) {
            unsigned u0 = *(const unsigned*)&xb[(size_t)cols[j][i] * DIM + lane * 2];
            float w0 = atts[j][i];
            lo0 += w0 * bf2f((unsigned short)(u0 & 0xffff));
            hi0 += w0 * bf2f((unsigned short)(u0 >> 16));
        }
        outv[j][lane * 2]     = ((lo0 + lo1) + (lo2 + lo3)) * 0.01f;
        outv[j][lane * 2 + 1] = ((hi0 + hi1) + (hi2 + hi3)) * 0.01f;
    }
    __syncthreads();

    int h = t >> 7, ch = t & 127;
    float xres[4];
#pragma unroll
    for (int jj = 0; jj < 4; ++jj)
        xres[jj] = x[(size_t)(n0 + h * 4 + jj) * DIM + ch];

    float a1[4] = {0, 0, 0, 0};
    for (int kc = 0; kc < 128; kc += 4) {
        float4 wv = *(const float4*)&w1[(size_t)ch * DIM + kc];
#pragma unroll
        for (int jj = 0; jj < 4; ++jj) {
            int j = h * 4 + jj;
            a1[jj] += wv.x * outv[j][kc] + wv.y * outv[j][kc + 1] + wv.z * outv[j][kc + 2] + wv.w * outv[j][kc + 3];
        }
    }
    float bias1 = bb1[ch];
#pragma unroll
    for (int jj = 0; jj < 4; ++jj) bufs[h * 4 + jj][ch] = a1[jj] + bias1;
    __syncthreads();

    {
        int j = t >> 5, l = t & 31;
        float s = 0.f, qq = 0.f;
#pragma unroll
        for (int i = 0; i < 4; ++i) { float v = bufs[j][l + 32 * i]; s += v; qq += v * v; }
#pragma unroll
        for (int off2 = 16; off2; off2 >>= 1) { s += __shfl_xor(s, off2); qq += __shfl_xor(qq, off2); }
        if (l == 0) {
            float mu = s * (1.f / 128.f);
            float var = qq * (1.f / 128.f) - mu * mu;
            mu_s[j] = mu; rs_s[j] = __builtin_amdgcn_rsqf(var + 1e-5f);
        }
    }
    __syncthreads();

    float g = lng[ch], bb = lnb[ch];
    float h2[4];
#pragma unroll
    for (int jj = 0; jj < 4; ++jj) {
        int j = h * 4 + jj;
        h2[jj] = fsilu((bufs[j][ch] - mu_s[j]) * rs_s[j] * g + bb);
    }
    __syncthreads();
#pragma unroll
    for (int jj = 0; jj < 4; ++jj) bufs[h * 4 + jj][ch] = h2[jj];
    __syncthreads();

    float a3[4] = {0, 0, 0, 0};
    for (int kc = 0; kc < 128; kc += 4) {
        float4 wv = *(const float4*)&w2[(size_t)ch * DIM + kc];
#pragma unroll
        for (int jj = 0; jj < 4; ++jj) {
            int j = h * 4 + jj;
            a3[jj] += wv.x * bufs[j][kc] + wv.y * bufs[j][kc + 1] + wv.z * bufs[j][kc + 2] + wv.w * bufs[j][kc + 3];
        }
    }
    float bias2 = bb2[ch];
    float hh[4];
#pragma unroll
    for (int jj = 0; jj < 4; ++jj) hh[jj] = a3[jj] + bias2 + xres[jj];
    __syncthreads();
#pragma unroll
    for (int jj = 0; jj < 4; ++jj) bufs[h * 4 + jj][ch] = hh[jj];
    __syncthreads();

    {
        int j = t >> 5, l = t & 31;
        float s = 0.f, qq = 0.f;
#pragma unroll
        for (int i = 0; i < 4; ++i) { float v = bufs[j][l + 32 * i]; s += v; qq += v * v; }
#pragma unroll
        for (int off2 = 16; off2; off2 >>= 1) { s += __shfl_xor(s, off2); qq += __shfl_xor(qq, off2); }
        if (l == 0) {
            float mu = s * (1.f / 128.f);
            float var = qq * (1.f / 128.f) - mu * mu;
            mu_s[j] = mu; rs_s[j] = __builtin_amdgcn_rsqf(var + 1e-5f);
        }
    }
    __syncthreads();

    float gf = gF[ch], bf = bF[ch];
#pragma unroll
    for (int jj = 0; jj < 4; ++jj) {
        int j = h * 4 + jj;
        float y = (hh[jj] - mu_s[j]) * rs_s[j] * gf + bf;
        out[(size_t)(n0 + j) * DIM + ch] = fsilu(y);
    }
}

extern "C" void kernel_launch(void* const* d_in, const int* in_sizes, int n_in,
                              void* d_out, int out_size, void* d_ws, size_t ws_size,
                              hipStream_t stream) {
    const float* h         = (const float*)d_in[0];
    const float* distances = (const float*)d_in[1];
    const float* edge_mask = (const float*)d_in[3];
    const float* lin_w     = (const float*)d_in[4];
    const float* lin_b     = (const float*)d_in[5];
    const float* att_w1    = (const float*)d_in[6];
    const float* att_b1    = (const float*)d_in[7];
    const float* att_w2    = (const float*)d_in[8];
    const float* att_b2    = (const float*)d_in[9];
    const float* att_w3    = (const float*)d_in[10];
    const float* att_b3    = (const float*)d_in[11];
    const float* nm_w1     = (const float*)d_in[12];
    const float* nm_b1     = (const float*)d_in[13];
    const float* nm_ln_g   = (const float*)d_in[14];
    const float* nm_ln_b   = (const float*)d_in[15];
    const float* nm_w2     = (const float*)d_in[16];
    const float* nm_b2     = (const float*)d_in[17];
    const float* ln_g      = (const float*)d_in[18];
    const float* ln_b      = (const float*)d_in[19];
    const int*   edges     = (const int*)d_in[20];
    float* out = (float*)d_out;

    const int N = N_NODES, E = E_EDGES;

    char* ws = (char*)d_ws;
    float* x            = (float*)ws;            ws += (size_t)N * DIM * 4;
    unsigned short* xb  = (unsigned short*)ws;   ws += (size_t)N * DIM * 2;
    int* cnt            = (int*)ws;              ws += (size_t)N * 4;
    int* off            = (int*)ws;              ws += (size_t)(N + 4) * 4;
    int2* adj2          = (int2*)ws;             ws += (size_t)N * CAP * 8;
    float* attv         = (float*)ws;            ws += (size_t)E * 4;
    unsigned short* w1b = (unsigned short*)ws;   ws += 256 * 256 * 2;
    float* w1p          = (float*)ws;            ws += 256 * 4;
    unsigned short* w2b = (unsigned short*)ws;   ws += 128 * 256 * 2;
    float* prf          = (float*)ws;            ws += (size_t)N * 256 * 4;
    unsigned short* pcb = (unsigned short*)ws;   ws += (size_t)N * 256 * 2;
    int4* flat          = (int4*)ws;             ws += (size_t)E * 16;

    hipMemsetAsync(cnt, 0, (size_t)N * 4, stream);

    pre_kernel<<<PRE_PREP_BLOCKS + PRE_LIN_BLOCKS + PRE_ADJ_BLOCKS, 256, 0, stream>>>(
        att_w1, att_w2, w1b, w1p, w2b,
        h, lin_w, lin_b, x, xb,
        edges, cnt, adj2, E);
    scan_kernel<<<1, 1024, 0, stream>>>(cnt, off);
    mid_kernel<<<MID_PRC_BLOCKS + MID_FLAT_BLOCKS, 256, 0, stream>>>(
        xb, w1b, att_b1, prf, pcb, adj2, cnt, off, distances, edge_mask, flat);
    edge_kernel<<<E / EPB, 512, 0, stream>>>(prf, pcb, flat, off,
                                             w1p, w2b, att_b2,
                                             att_w3, att_b3, attv);
    node_kernel<<<N / NPB, 256, 0, stream>>>(attv, adj2, cnt, off, xb, x,
                                             nm_w1, nm_b1, nm_ln_g, nm_ln_b,
                                             nm_w2, nm_b2, ln_g, ln_b, out, E);
}

// Round 4
// 425.929 us; speedup vs baseline: 1.1244x; 1.0833x over previous
//
#include <hip/hip_runtime.h>
#include <hip/hip_bf16.h>

#define N_NODES 20000
#define E_EDGES 640000
#define DIM 128
#define CAP 96    // Poisson(32) max degree ~65; 96 is >10-sigma safe
#define EPB 64    // edges per block in edge_kernel
#define NPB 8     // nodes per block in node_kernel / flat build
#define XST 264   // padded ushort stride for [64][256] LDS tile

typedef __attribute__((ext_vector_type(8))) short bf16x8;
typedef __attribute__((ext_vector_type(4))) float f32x4;

#define LOG2E 1.44269504f
__device__ __forceinline__ float fsilu(float x) {
    return x * __builtin_amdgcn_rcpf(1.f + __builtin_amdgcn_exp2f(-LOG2E * x));
}
__device__ __forceinline__ float fsig(float x) {
    return __builtin_amdgcn_rcpf(1.f + __builtin_amdgcn_exp2f(-LOG2E * x));
}

__device__ __forceinline__ unsigned short f2bf(float x) {
    union { float f; unsigned u; } v; v.f = x;
    unsigned r = (v.u + 0x7fffu + ((v.u >> 16) & 1u)) >> 16;
    return (unsigned short)r;
}
__device__ __forceinline__ float bf2f(unsigned short s) {
    union { unsigned u; float f; } v; v.u = ((unsigned)s) << 16;
    return v.f;
}
// pack two floats to packed bf16 {lo,hi} with round-half-up
__device__ __forceinline__ unsigned pack_bf16(float lo, float hi) {
    union { float f; unsigned u; } a, b; a.f = lo; b.f = hi;
    unsigned ul = a.u + 0x8000u, uh = b.u + 0x8000u;
    return __builtin_amdgcn_perm(uh, ul, 0x07060302u);
}

// ------- fused pre-kernel: weight prep (64) + lin (625) + adj build (2500) -------
#define PRE_PREP_BLOCKS 64
#define PRE_LIN_BLOCKS  625   // 32 nodes per block
#define PRE_ADJ_BLOCKS  2500
__global__ __launch_bounds__(256) void pre_kernel(
    const float* __restrict__ w1, const float* __restrict__ w2,
    unsigned short* __restrict__ w1b, float* __restrict__ w1p,
    unsigned short* __restrict__ w2b,
    const float* __restrict__ h, const float* __restrict__ lw,
    const float* __restrict__ lb, float* __restrict__ x,
    unsigned short* __restrict__ xb,
    const int* __restrict__ edges, int* __restrict__ cnt,
    int2* __restrict__ adj2, int E) {
    __shared__ float hs[32][128];
    int b = blockIdx.x;
    int t = threadIdx.x;

    if (b < PRE_PREP_BLOCKS) {
        int i = b * 256 + t;
        const int stride = PRE_PREP_BLOCKS * 256;
        for (int idx = i; idx < 256 * 256; idx += stride) {
            int o = idx >> 8, k = idx & 255;
            w1b[idx] = f2bf(w1[o * 257 + k]);
        }
        // w2b k-order permuted: within each 32-chunk b2: pos b2+2l <- k=b2+l ; b2+2l+1 <- k=b2+16+l
        for (int idx = i; idx < 128 * 256; idx += stride) {
            int n2 = idx >> 8, p = idx & 255;
            int bb = p & ~31, off = p & 31;
            int ksrc = bb + (off >> 1) + ((off & 1) << 4);
            w2b[idx] = f2bf(w2[n2 * 256 + ksrc]);
        }
        // w1last in the SAME permuted order as the a1 LDS tile / w2b k-order
        for (int idx = i; idx < 256; idx += stride) {
            int bb = idx & ~31, off = idx & 31;
            int ksrc = bb + (off >> 1) + ((off & 1) << 4);
            w1p[idx] = w1[ksrc * 257 + 256];
        }
    } else if (b < PRE_PREP_BLOCKS + PRE_LIN_BLOCKS) {
        int nb = b - PRE_PREP_BLOCKS;
        int n0 = nb * 32;
        int ch = t & 127, g = t >> 7;   // g in {0,1}, 16 nodes each
#pragma unroll
        for (int j = 0; j < 16; ++j) hs[g * 16 + j][ch] = h[(size_t)(n0 + g * 16 + j) * DIM + ch];
        __syncthreads();
        float acc[16];
#pragma unroll
        for (int j = 0; j < 16; ++j) acc[j] = 0.f;
        for (int kc = 0; kc < 128; kc += 4) {
            float4 wv = *(const float4*)&lw[(size_t)ch * DIM + kc];
#pragma unroll
            for (int j = 0; j < 16; ++j)
                acc[j] += wv.x * hs[g * 16 + j][kc] + wv.y * hs[g * 16 + j][kc + 1]
                        + wv.z * hs[g * 16 + j][kc + 2] + wv.w * hs[g * 16 + j][kc + 3];
        }
        float bias = lb[ch];
#pragma unroll
        for (int j = 0; j < 16; ++j) {
            float v = acc[j] + bias;
            int n = n0 + g * 16 + j;
            x[(size_t)n * DIM + ch] = v;
            xb[(size_t)n * DIM + ch] = f2bf(v);
        }
    } else {
        int e = (b - PRE_PREP_BLOCKS - PRE_LIN_BLOCKS) * 256 + t;
        if (e < E) {
            int r = edges[e];
            int col = edges[E + e];
            int slot = atomicAdd(&cnt[r], 1);
            if (slot < CAP) { int2 v; v.x = e; v.y = col; adj2[(size_t)r * CAP + slot] = v; }
        }
    }
}

// ------- scan_kernel: exclusive prefix sum of clamped cnt -> off[N+1] -------
__global__ __launch_bounds__(1024) void scan_kernel(const int* __restrict__ cnt,
                                                    int* __restrict__ off) {
    __shared__ int part[1024];
    int t = threadIdx.x;
    int base = t * 20;
    int loc[20];
    int s = 0;
#pragma unroll
    for (int i = 0; i < 20; ++i) {
        int idx = base + i;
        int v = 0;
        if (idx < N_NODES) { v = cnt[idx]; v = v > CAP ? CAP : v; }
        loc[i] = s; s += v;
    }
    part[t] = s;
    __syncthreads();
    int run = s;
    for (int d = 1; d < 1024; d <<= 1) {
        int v = (t >= d) ? part[t - d] : 0;
        __syncthreads();
        part[t] += v;
        __syncthreads();
    }
    int ex = part[t] - run;
#pragma unroll
    for (int i = 0; i < 20; ++i) {
        int idx = base + i;
        if (idx < N_NODES) off[idx] = ex + loc[i];
    }
    if (t == 1023) off[N_NODES] = part[1023];
}

// ------- mid_kernel: prc (1250 blocks) + flat edge-list build (2500 blocks) -------
// prc: prb[n][o] = bf16(x@W1r^T + b1); pcb[n][o] = bf16(x@W1c^T)
// flat: adj-ordered int4 {row, col, bits(d*em), bits(em)}
#define MID_PRC_BLOCKS 1250    // N/16
#define MID_FLAT_BLOCKS 2500   // N/8
__global__ __launch_bounds__(256) void mid_kernel(
    const unsigned short* __restrict__ xb,
    const unsigned short* __restrict__ w1b,
    const float* __restrict__ b1,
    unsigned short* __restrict__ prb, unsigned short* __restrict__ pcb,
    const int2* __restrict__ adj2, const int* __restrict__ cnt,
    const int* __restrict__ off,
    const float* __restrict__ dist, const float* __restrict__ emask,
    int4* __restrict__ flat) {
    int b = blockIdx.x;
    if (b < MID_PRC_BLOCKS) {
        int n0 = b * 16;
        int w = threadIdx.x >> 6, lane = threadIdx.x & 63;
        int lrow = lane & 15, quad = lane >> 4;

        bf16x8 a[4];
#pragma unroll
        for (int kk = 0; kk < 4; ++kk)
            a[kk] = *(const bf16x8*)&xb[(size_t)(n0 + lrow) * DIM + kk * 32 + quad * 8];

        f32x4 z = {0.f, 0.f, 0.f, 0.f};
#pragma unroll
        for (int i = 0; i < 8; ++i) {
            int gt = w * 8 + i;
            int half = gt >> 4;            // 0 -> prb, 1 -> pcb
            int obase = (gt & 15) * 16;
            f32x4 acc = z;
#pragma unroll
            for (int kk = 0; kk < 4; ++kk) {
                bf16x8 bfrag = *(const bf16x8*)&w1b[(size_t)(obase + lrow) * 256 + half * 128 + kk * 32 + quad * 8];
                acc = __builtin_amdgcn_mfma_f32_16x16x32_bf16(a[kk], bfrag, acc, 0, 0, 0);
            }
            int o = obase + lrow;
            if (half == 0) {
                float bias = b1[o];
#pragma unroll
                for (int r = 0; r < 4; ++r)
                    prb[(size_t)(n0 + quad * 4 + r) * 256 + o] = f2bf(acc[r] + bias);
            } else {
#pragma unroll
                for (int r = 0; r < 4; ++r)
                    pcb[(size_t)(n0 + quad * 4 + r) * 256 + o] = f2bf(acc[r]);
            }
        }
    } else {
        int fb = b - MID_PRC_BLOCKS;
        int n0 = fb * NPB;
        int jg = threadIdx.x >> 5, l = threadIdx.x & 31;
        int n = n0 + jg;
        int c = cnt[n]; c = c > CAP ? CAP : c;
        int o = off[n];
        const int2* al = adj2 + (size_t)n * CAP;
        for (int i = l; i < c; i += 32) {
            int2 v = al[i];
            float em = emask[v.x];
            float dv = dist[v.x] * em;
            int4 wv;
            union { float f; int i; } u1, u2; u1.f = dv; u2.f = em;
            wv.x = n; wv.y = v.y; wv.z = u1.i; wv.w = u2.i;
            flat[o + i] = wv;
        }
    }
}

// ---------------- Kernel 4: edge MLP over flat adj-ordered list ----------------
// 10000 independent blocks, one 64-edge tile each; rows arrive grouped so
// prb[row] (bf16, bias folded) is L1-hot; pcb[col] is the single random
// stream. att written flat-ordered (coalesced consume in node_kernel).
__global__ __launch_bounds__(512, 4) void edge_kernel(
    const unsigned short* __restrict__ prb, const unsigned short* __restrict__ pcb,
    const int4* __restrict__ flat, const int* __restrict__ off,
    const float* __restrict__ w1p,
    const unsigned short* __restrict__ w2b, const float* __restrict__ b2,
    const float* __restrict__ w3, const float* __restrict__ b3v,
    float* __restrict__ attv) {
    __shared__ unsigned short buf[EPB * XST];
    __shared__ float part[8][EPB];
    __shared__ float w1ps[256];
    __shared__ float dvals[EPB], emv[EPB];
    __shared__ int ridx[EPB], cidx[EPB];

    int tid = threadIdx.x;
    int eb = blockIdx.x * EPB;

    if (tid < EPB) {
        int count = off[N_NODES];
        int idx = eb + tid;
        int4 v;
        if (idx < count) v = flat[idx];
        else { v.x = 0; v.y = 0; v.z = 0; v.w = 0; }
        ridx[tid] = v.x; cidx[tid] = v.y;
        union { int i; float f; } a, bu; a.i = v.z; bu.i = v.w;
        dvals[tid] = a.f; emv[tid] = bu.f;
    }
    if (tid >= 64 && tid < 320) w1ps[tid - 64] = w1p[tid - 64];

    int wave = tid >> 6, lane = tid & 63;
    int lrow = lane & 15, quad = lane >> 4;
    int n2 = wave * 16 + lrow;
    float bias2 = b2[n2];
    float w3v = w3[n2];

    __syncthreads();

    // ---- gather + layer-1 epilogue: thread (ge = tid>>3, cb = tid&7) owns one
    // 32-neuron chunk of one edge. Pairs (o, o+16) pack to the permuted
    // position matching w2b's k-order.
    {
        int ge = tid >> 3, cb = tid & 7;
        const unsigned short* prow = prb + (size_t)ridx[ge] * 256 + cb * 32;
        const unsigned short* pcp  = pcb + (size_t)cidx[ge] * 256 + cb * 32;
        float d = dvals[ge];
        unsigned* wrow = (unsigned*)&buf[ge * XST + cb * 32];
        const float* wp = &w1ps[cb * 32];

        bf16x8 pA = *(const bf16x8*)&prow[0];
        bf16x8 pB = *(const bf16x8*)&prow[16];
        bf16x8 qA = *(const bf16x8*)&pcp[0];
        bf16x8 qB = *(const bf16x8*)&pcp[16];
#pragma unroll
        for (int l = 0; l < 8; ++l) {
            float s0 = bf2f((unsigned short)pA[l]) + bf2f((unsigned short)qA[l]) + d * wp[2 * l];
            float s1 = bf2f((unsigned short)pB[l]) + bf2f((unsigned short)qB[l]) + d * wp[2 * l + 1];
            wrow[l] = pack_bf16(fsilu(s0), fsilu(s1));
        }
        pA = *(const bf16x8*)&prow[8];
        pB = *(const bf16x8*)&prow[24];
        qA = *(const bf16x8*)&pcp[8];
        qB = *(const bf16x8*)&pcp[24];
#pragma unroll
        for (int l = 0; l < 8; ++l) {
            float s0 = bf2f((unsigned short)pA[l]) + bf2f((unsigned short)qA[l]) + d * wp[16 + 2 * l];
            float s1 = bf2f((unsigned short)pB[l]) + bf2f((unsigned short)qB[l]) + d * wp[16 + 2 * l + 1];
            wrow[8 + l] = pack_bf16(fsilu(s0), fsilu(s1));
        }
    }
    __syncthreads();

    // ---- layer 2: wave covers 16 of 128 N2 (k-order permuted on both sides)
    f32x4 zz = {0.f, 0.f, 0.f, 0.f};
    f32x4 acc2[4];
#pragma unroll
    for (int mt = 0; mt < 4; ++mt) acc2[mt] = zz;

    for (int kk = 0; kk < 8; ++kk) {
        int ka = kk * 32 + quad * 8;
        bf16x8 bfrag = *(const bf16x8*)&w2b[(size_t)n2 * 256 + ka];
#pragma unroll
        for (int mt = 0; mt < 4; ++mt) {
            bf16x8 a = *(bf16x8*)&buf[(mt * 16 + lrow) * XST + ka];
            acc2[mt] = __builtin_amdgcn_mfma_f32_16x16x32_bf16(a, bfrag, acc2[mt], 0, 0, 0);
        }
    }

    // ---- layer 3 in registers
    float s[4][4];
#pragma unroll
    for (int mt = 0; mt < 4; ++mt)
#pragma unroll
        for (int r = 0; r < 4; ++r)
            s[mt][r] = fsilu(acc2[mt][r] + bias2) * w3v;
#pragma unroll
    for (int off2 = 1; off2 < 16; off2 <<= 1) {
#pragma unroll
        for (int mt = 0; mt < 4; ++mt)
#pragma unroll
            for (int r = 0; r < 4; ++r)
                s[mt][r] += __shfl_xor(s[mt][r], off2);
    }
    if (lrow == 0) {
#pragma unroll
        for (int mt = 0; mt < 4; ++mt)
#pragma unroll
            for (int r = 0; r < 4; ++r)
                part[wave][mt * 16 + quad * 4 + r] = s[mt][r];
    }
    __syncthreads();

    if (tid < EPB) {
        float ssum = b3v[0];
#pragma unroll
        for (int w = 0; w < 8; ++w) ssum += part[w][tid];
        attv[eb + tid] = fsig(ssum) * emv[tid];
    }
}

// ---------------- Kernel 5: aggregate + node MLP + LNs ----------------
__global__ __launch_bounds__(256) void node_kernel(
    const float* __restrict__ attv, const int2* __restrict__ adj2,
    const int* __restrict__ cnt, const int* __restrict__ off,
    const unsigned short* __restrict__ xb,
    const float* __restrict__ x,
    const float* __restrict__ w1, const float* __restrict__ bb1,
    const float* __restrict__ lng, const float* __restrict__ lnb,
    const float* __restrict__ w2, const float* __restrict__ bb2,
    const float* __restrict__ gF, const float* __restrict__ bF,
    float* __restrict__ out, int E) {
    __shared__ float atts[NPB][CAP];
    __shared__ int   cols[NPB][CAP];
    __shared__ float outv[NPB][128];
    __shared__ float bufs[NPB][128];
    __shared__ float mu_s[NPB], rs_s[NPB];
    __shared__ int cnts[NPB];

    int t = threadIdx.x;
    int n0 = blockIdx.x * NPB;

    if (t < NPB) { int c = cnt[n0 + t]; cnts[t] = c > CAP ? CAP : c; }
    __syncthreads();

    {
        int jg = t >> 5, l = t & 31;
        int c = cnts[jg];
        const int2* al = adj2 + (size_t)(n0 + jg) * CAP;
        const float* av = attv + off[n0 + jg];
        for (int i = l; i < c; i += 32) {
            atts[jg][i] = av[i];
            cols[jg][i] = al[i].y;
        }
    }
    __syncthreads();

    int w = t >> 6, lane = t & 63;
#pragma unroll
    for (int jj = 0; jj < 2; ++jj) {
        int j = w * 2 + jj;
        int c = cnts[j];
        float lo0 = 0.f, hi0 = 0.f, lo1 = 0.f, hi1 = 0.f;
        float lo2 = 0.f, hi2 = 0.f, lo3 = 0.f, hi3 = 0.f;
        int i = 0;
        for (; i + 3 < c; i += 4) {
            unsigned u0 = *(const unsigned*)&xb[(size_t)cols[j][i]     * DIM + lane * 2];
            unsigned u1 = *(const unsigned*)&xb[(size_t)cols[j][i + 1] * DIM + lane * 2];
            unsigned u2 = *(const unsigned*)&xb[(size_t)cols[j][i + 2] * DIM + lane * 2];
            unsigned u3 = *(const unsigned*)&xb[(size_t)cols[j][i + 3] * DIM + lane * 2];
            float w0 = atts[j][i], w1v = atts[j][i + 1], w2v = atts[j][i + 2], w3v = atts[j][i + 3];
            lo0 += w0 * bf2f((unsigned short)(u0 & 0xffff)); hi0 += w0 * bf2f((unsigned short)(u0 >> 16));
            lo1 += w1v * bf2f((unsigned short)(u1 & 0xffff)); hi1 += w1v * bf2f((unsigned short)(u1 >> 16));
            lo2 += w2v * bf2f((unsigned short)(u2 & 0xffff)); hi2 += w2v * bf2f((unsigned short)(u2 >> 16));
            lo3 += w3v * bf2f((unsigned short)(u3 & 0xffff)); hi3 += w3v * bf2f((unsigned short)(u3 >> 16));
        }
        for (; i < c; ++i) {
            unsigned u0 = *(const unsigned*)&xb[(size_t)cols[j][i] * DIM + lane * 2];
            float w0 = atts[j][i];
            lo0 += w0 * bf2f((unsigned short)(u0 & 0xffff));
            hi0 += w0 * bf2f((unsigned short)(u0 >> 16));
        }
        outv[j][lane * 2]     = ((lo0 + lo1) + (lo2 + lo3)) * 0.01f;
        outv[j][lane * 2 + 1] = ((hi0 + hi1) + (hi2 + hi3)) * 0.01f;
    }
    __syncthreads();

    int h = t >> 7, ch = t & 127;
    float xres[4];
#pragma unroll
    for (int jj = 0; jj < 4; ++jj)
        xres[jj] = x[(size_t)(n0 + h * 4 + jj) * DIM + ch];

    float a1[4] = {0, 0, 0, 0};
    for (int kc = 0; kc < 128; kc += 4) {
        float4 wv = *(const float4*)&w1[(size_t)ch * DIM + kc];
#pragma unroll
        for (int jj = 0; jj < 4; ++jj) {
            int j = h * 4 + jj;
            float4 ov = *(const float4*)&outv[j][kc];
            a1[jj] += wv.x * ov.x + wv.y * ov.y + wv.z * ov.z + wv.w * ov.w;
        }
    }
    float bias1 = bb1[ch];
#pragma unroll
    for (int jj = 0; jj < 4; ++jj) bufs[h * 4 + jj][ch] = a1[jj] + bias1;
    __syncthreads();

    {
        int j = t >> 5, l = t & 31;
        float s = 0.f, qq = 0.f;
#pragma unroll
        for (int i = 0; i < 4; ++i) { float v = bufs[j][l + 32 * i]; s += v; qq += v * v; }
#pragma unroll
        for (int off2 = 16; off2; off2 >>= 1) { s += __shfl_xor(s, off2); qq += __shfl_xor(qq, off2); }
        if (l == 0) {
            float mu = s * (1.f / 128.f);
            float var = qq * (1.f / 128.f) - mu * mu;
            mu_s[j] = mu; rs_s[j] = __builtin_amdgcn_rsqf(var + 1e-5f);
        }
    }
    __syncthreads();

    float g = lng[ch], bb = lnb[ch];
    float h2[4];
#pragma unroll
    for (int jj = 0; jj < 4; ++jj) {
        int j = h * 4 + jj;
        h2[jj] = fsilu((bufs[j][ch] - mu_s[j]) * rs_s[j] * g + bb);
    }
    __syncthreads();
#pragma unroll
    for (int jj = 0; jj < 4; ++jj) bufs[h * 4 + jj][ch] = h2[jj];
    __syncthreads();

    float a3[4] = {0, 0, 0, 0};
    for (int kc = 0; kc < 128; kc += 4) {
        float4 wv = *(const float4*)&w2[(size_t)ch * DIM + kc];
#pragma unroll
        for (int jj = 0; jj < 4; ++jj) {
            int j = h * 4 + jj;
            float4 bv = *(const float4*)&bufs[j][kc];
            a3[jj] += wv.x * bv.x + wv.y * bv.y + wv.z * bv.z + wv.w * bv.w;
        }
    }
    float bias2 = bb2[ch];
    float hh[4];
#pragma unroll
    for (int jj = 0; jj < 4; ++jj) hh[jj] = a3[jj] + bias2 + xres[jj];
    __syncthreads();
#pragma unroll
    for (int jj = 0; jj < 4; ++jj) bufs[h * 4 + jj][ch] = hh[jj];
    __syncthreads();

    {
        int j = t >> 5, l = t & 31;
        float s = 0.f, qq = 0.f;
#pragma unroll
        for (int i = 0; i < 4; ++i) { float v = bufs[j][l + 32 * i]; s += v; qq += v * v; }
#pragma unroll
        for (int off2 = 16; off2; off2 >>= 1) { s += __shfl_xor(s, off2); qq += __shfl_xor(qq, off2); }
        if (l == 0) {
            float mu = s * (1.f / 128.f);
            float var = qq * (1.f / 128.f) - mu * mu;
            mu_s[j] = mu; rs_s[j] = __builtin_amdgcn_rsqf(var + 1e-5f);
        }
    }
    __syncthreads();

    float gf = gF[ch], bf = bF[ch];
#pragma unroll
    for (int jj = 0; jj < 4; ++jj) {
        int j = h * 4 + jj;
        float y = (hh[jj] - mu_s[j]) * rs_s[j] * gf + bf;
        out[(size_t)(n0 + j) * DIM + ch] = fsilu(y);
    }
}

extern "C" void kernel_launch(void* const* d_in, const int* in_sizes, int n_in,
                              void* d_out, int out_size, void* d_ws, size_t ws_size,
                              hipStream_t stream) {
    const float* h         = (const float*)d_in[0];
    const float* distances = (const float*)d_in[1];
    const float* edge_mask = (const float*)d_in[3];
    const float* lin_w     = (const float*)d_in[4];
    const float* lin_b     = (const float*)d_in[5];
    const float* att_w1    = (const float*)d_in[6];
    const float* att_b1    = (const float*)d_in[7];
    const float* att_w2    = (const float*)d_in[8];
    const float* att_b2    = (const float*)d_in[9];
    const float* att_w3    = (const float*)d_in[10];
    const float* att_b3    = (const float*)d_in[11];
    const float* nm_w1     = (const float*)d_in[12];
    const float* nm_b1     = (const float*)d_in[13];
    const float* nm_ln_g   = (const float*)d_in[14];
    const float* nm_ln_b   = (const float*)d_in[15];
    const float* nm_w2     = (const float*)d_in[16];
    const float* nm_b2     = (const float*)d_in[17];
    const float* ln_g      = (const float*)d_in[18];
    const float* ln_b      = (const float*)d_in[19];
    const int*   edges     = (const int*)d_in[20];
    float* out = (float*)d_out;

    const int N = N_NODES, E = E_EDGES;

    char* ws = (char*)d_ws;
    float* x            = (float*)ws;            ws += (size_t)N * DIM * 4;
    unsigned short* xb  = (unsigned short*)ws;   ws += (size_t)N * DIM * 2;
    int* cnt            = (int*)ws;              ws += (size_t)N * 4;
    int* off            = (int*)ws;              ws += (size_t)(N + 4) * 4;
    int2* adj2          = (int2*)ws;             ws += (size_t)N * CAP * 8;
    float* attv         = (float*)ws;            ws += (size_t)E * 4;
    unsigned short* w1b = (unsigned short*)ws;   ws += 256 * 256 * 2;
    float* w1p          = (float*)ws;            ws += 256 * 4;
    unsigned short* w2b = (unsigned short*)ws;   ws += 128 * 256 * 2;
    unsigned short* prb = (unsigned short*)ws;   ws += (size_t)N * 256 * 2;
    unsigned short* pcb = (unsigned short*)ws;   ws += (size_t)N * 256 * 2;
    int4* flat          = (int4*)ws;             ws += (size_t)E * 16;

    hipMemsetAsync(cnt, 0, (size_t)N * 4, stream);

    pre_kernel<<<PRE_PREP_BLOCKS + PRE_LIN_BLOCKS + PRE_ADJ_BLOCKS, 256, 0, stream>>>(
        att_w1, att_w2, w1b, w1p, w2b,
        h, lin_w, lin_b, x, xb,
        edges, cnt, adj2, E);
    scan_kernel<<<1, 1024, 0, stream>>>(cnt, off);
    mid_kernel<<<MID_PRC_BLOCKS + MID_FLAT_BLOCKS, 256, 0, stream>>>(
        xb, w1b, att_b1, prb, pcb, adj2, cnt, off, distances, edge_mask, flat);
    edge_kernel<<<E / EPB, 512, 0, stream>>>(prb, pcb, flat, off,
                                             w1p, w2b, att_b2,
                                             att_w3, att_b3, attv);
    node_kernel<<<N / NPB, 256, 0, stream>>>(attv, adj2, cnt, off, xb, x,
                                             nm_w1, nm_b1, nm_ln_g, nm_ln_b,
                                             nm_w2, nm_b2, ln_g, ln_b, out, E);
}

// Round 5
// 413.881 us; speedup vs baseline: 1.1571x; 1.0291x over previous
//
#include <hip/hip_runtime.h>
#include <hip/hip_bf16.h>

#define N_NODES 20000
#define E_EDGES 640000
#define DIM 128
#define CAP 96    // Poisson(32) max degree ~65; 96 is >10-sigma safe
#define EPB 64    // edges per block in edge_kernel
#define NPB 8     // nodes per block in node_kernel / flat build
#define XST 264   // padded ushort stride for [64][256] LDS tile

typedef __attribute__((ext_vector_type(8))) short bf16x8;
typedef __attribute__((ext_vector_type(4))) float f32x4;
typedef __attribute__((ext_vector_type(4))) unsigned u32x4;

#define LOG2E 1.44269504f
__device__ __forceinline__ float fsilu(float x) {
    return x * __builtin_amdgcn_rcpf(1.f + __builtin_amdgcn_exp2f(-LOG2E * x));
}
__device__ __forceinline__ float fsig(float x) {
    return __builtin_amdgcn_rcpf(1.f + __builtin_amdgcn_exp2f(-LOG2E * x));
}

__device__ __forceinline__ unsigned short f2bf(float x) {
    union { float f; unsigned u; } v; v.f = x;
    unsigned r = (v.u + 0x7fffu + ((v.u >> 16) & 1u)) >> 16;
    return (unsigned short)r;
}
__device__ __forceinline__ float bf2f(unsigned short s) {
    union { unsigned u; float f; } v; v.u = ((unsigned)s) << 16;
    return v.f;
}
// pack two floats to packed bf16 {lo,hi} with round-half-up
__device__ __forceinline__ unsigned pack_bf16(float lo, float hi) {
    union { float f; unsigned u; } a, b; a.f = lo; b.f = hi;
    unsigned ul = a.u + 0x8000u, uh = b.u + 0x8000u;
    return __builtin_amdgcn_perm(uh, ul, 0x07060302u);
}

// ------- fused pre-kernel: weight prep (64) + lin (625) + adj build (2500) -------
#define PRE_PREP_BLOCKS 64
#define PRE_LIN_BLOCKS  625   // 32 nodes per block
#define PRE_ADJ_BLOCKS  2500
__global__ __launch_bounds__(256) void pre_kernel(
    const float* __restrict__ w1, const float* __restrict__ w2,
    unsigned short* __restrict__ w1b, float* __restrict__ w1p,
    unsigned short* __restrict__ w2b,
    const float* __restrict__ h, const float* __restrict__ lw,
    const float* __restrict__ lb, float* __restrict__ x,
    unsigned short* __restrict__ xb,
    const int* __restrict__ edges,
    const float* __restrict__ dist, const float* __restrict__ emask,
    int* __restrict__ cnt,
    int* __restrict__ adjc, float2* __restrict__ dm, int E) {
    __shared__ float hs[32][128];
    int b = blockIdx.x;
    int t = threadIdx.x;

    if (b < PRE_PREP_BLOCKS) {
        int i = b * 256 + t;
        const int stride = PRE_PREP_BLOCKS * 256;
        for (int idx = i; idx < 256 * 256; idx += stride) {
            int o = idx >> 8, k = idx & 255;
            w1b[idx] = f2bf(w1[o * 257 + k]);
        }
        // w2b k-order permuted: within each 32-chunk b2: pos b2+2l <- k=b2+l ; b2+2l+1 <- k=b2+16+l
        for (int idx = i; idx < 128 * 256; idx += stride) {
            int n2 = idx >> 8, p = idx & 255;
            int bb = p & ~31, off = p & 31;
            int ksrc = bb + (off >> 1) + ((off & 1) << 4);
            w2b[idx] = f2bf(w2[n2 * 256 + ksrc]);
        }
        // w1last in the SAME permuted order as the a1 LDS tile / w2b k-order
        for (int idx = i; idx < 256; idx += stride) {
            int bb = idx & ~31, off = idx & 31;
            int ksrc = bb + (off >> 1) + ((off & 1) << 4);
            w1p[idx] = w1[ksrc * 257 + 256];
        }
    } else if (b < PRE_PREP_BLOCKS + PRE_LIN_BLOCKS) {
        int nb = b - PRE_PREP_BLOCKS;
        int n0 = nb * 32;
        int ch = t & 127, g = t >> 7;   // g in {0,1}, 16 nodes each
#pragma unroll
        for (int j = 0; j < 16; ++j) hs[g * 16 + j][ch] = h[(size_t)(n0 + g * 16 + j) * DIM + ch];
        __syncthreads();
        float acc[16];
#pragma unroll
        for (int j = 0; j < 16; ++j) acc[j] = 0.f;
        for (int kc = 0; kc < 128; kc += 4) {
            float4 wv = *(const float4*)&lw[(size_t)ch * DIM + kc];
#pragma unroll
            for (int j = 0; j < 16; ++j)
                acc[j] += wv.x * hs[g * 16 + j][kc] + wv.y * hs[g * 16 + j][kc + 1]
                        + wv.z * hs[g * 16 + j][kc + 2] + wv.w * hs[g * 16 + j][kc + 3];
        }
        float bias = lb[ch];
#pragma unroll
        for (int j = 0; j < 16; ++j) {
            float v = acc[j] + bias;
            int n = n0 + g * 16 + j;
            x[(size_t)n * DIM + ch] = v;
            xb[(size_t)n * DIM + ch] = f2bf(v);
        }
    } else {
        int e = (b - PRE_PREP_BLOCKS - PRE_LIN_BLOCKS) * 256 + t;
        if (e < E) {
            int r = edges[e];
            int col = edges[E + e];
            float em = emask[e];          // coalesced here (sequential e)
            float dv = dist[e] * em;
            int slot = atomicAdd(&cnt[r], 1);
            if (slot < CAP) {
                adjc[(size_t)r * CAP + slot] = col;
                float2 de; de.x = dv; de.y = em;
                dm[(size_t)r * CAP + slot] = de;
            }
        }
    }
}

// ------- scan_kernel: exclusive prefix sum of clamped cnt -> off[N+1] -------
// shfl-based: per-thread 20-node run, wave inclusive scan, 16-entry 2nd level.
__global__ __launch_bounds__(1024) void scan_kernel(const int* __restrict__ cnt,
                                                    int* __restrict__ off) {
    __shared__ int wsum[16], wbase[16];
    int t = threadIdx.x;
    int lane = t & 63, wid = t >> 6;
    int base = t * 20;
    int loc[20];
    int s = 0;
#pragma unroll
    for (int i = 0; i < 20; ++i) {
        int idx = base + i;
        int v = 0;
        if (idx < N_NODES) { v = cnt[idx]; v = v > CAP ? CAP : v; }
        loc[i] = s; s += v;
    }
    int inc = s;
#pragma unroll
    for (int d = 1; d < 64; d <<= 1) {
        int u = __shfl_up(inc, d);
        if (lane >= d) inc += u;
    }
    if (lane == 63) wsum[wid] = inc;
    __syncthreads();
    if (t < 16) {
        int v = wsum[t];
        int inc2 = v;
#pragma unroll
        for (int d = 1; d < 16; d <<= 1) {
            int u = __shfl_up(inc2, d);
            if (t >= d) inc2 += u;
        }
        wbase[t] = inc2 - v;
        if (t == 15) off[N_NODES] = inc2;
    }
    __syncthreads();
    int ex = wbase[wid] + inc - s;
#pragma unroll
    for (int i = 0; i < 20; ++i) {
        int idx = base + i;
        if (idx < N_NODES) off[idx] = ex + loc[i];
    }
}

// ------- mid_kernel: prc (1250 blocks) + flat edge-list build (2500 blocks) -------
// prc: prb[n][o] = bf16(x@W1r^T + b1); pcb[n][o] = bf16(x@W1c^T)
// flat: adj-ordered int4 {row, col, bits(d*em), bits(em)} -- pure sequential copy now
#define MID_PRC_BLOCKS 1250    // N/16
#define MID_FLAT_BLOCKS 2500   // N/8
__global__ __launch_bounds__(256) void mid_kernel(
    const unsigned short* __restrict__ xb,
    const unsigned short* __restrict__ w1b,
    const float* __restrict__ b1,
    unsigned short* __restrict__ prb, unsigned short* __restrict__ pcb,
    const int* __restrict__ adjc, const float2* __restrict__ dm,
    const int* __restrict__ cnt, const int* __restrict__ off,
    int4* __restrict__ flat) {
    int b = blockIdx.x;
    if (b < MID_PRC_BLOCKS) {
        int n0 = b * 16;
        int w = threadIdx.x >> 6, lane = threadIdx.x & 63;
        int lrow = lane & 15, quad = lane >> 4;

        bf16x8 a[4];
#pragma unroll
        for (int kk = 0; kk < 4; ++kk)
            a[kk] = *(const bf16x8*)&xb[(size_t)(n0 + lrow) * DIM + kk * 32 + quad * 8];

        f32x4 z = {0.f, 0.f, 0.f, 0.f};
#pragma unroll
        for (int i = 0; i < 8; ++i) {
            int gt = w * 8 + i;
            int half = gt >> 4;            // 0 -> prb, 1 -> pcb
            int obase = (gt & 15) * 16;
            f32x4 acc = z;
#pragma unroll
            for (int kk = 0; kk < 4; ++kk) {
                bf16x8 bfrag = *(const bf16x8*)&w1b[(size_t)(obase + lrow) * 256 + half * 128 + kk * 32 + quad * 8];
                acc = __builtin_amdgcn_mfma_f32_16x16x32_bf16(a[kk], bfrag, acc, 0, 0, 0);
            }
            int o = obase + lrow;
            if (half == 0) {
                float bias = b1[o];
#pragma unroll
                for (int r = 0; r < 4; ++r)
                    prb[(size_t)(n0 + quad * 4 + r) * 256 + o] = f2bf(acc[r] + bias);
            } else {
#pragma unroll
                for (int r = 0; r < 4; ++r)
                    pcb[(size_t)(n0 + quad * 4 + r) * 256 + o] = f2bf(acc[r]);
            }
        }
    } else {
        int fb = b - MID_PRC_BLOCKS;
        int n0 = fb * NPB;
        int jg = threadIdx.x >> 5, l = threadIdx.x & 31;
        int n = n0 + jg;
        int c = cnt[n]; c = c > CAP ? CAP : c;
        int o = off[n];
        const int* al = adjc + (size_t)n * CAP;
        const float2* dl = dm + (size_t)n * CAP;
        for (int i = l; i < c; i += 32) {
            float2 de = dl[i];
            int4 wv;
            union { float f; int i; } u1, u2; u1.f = de.x; u2.f = de.y;
            wv.x = n; wv.y = al[i]; wv.z = u1.i; wv.w = u2.i;
            flat[o + i] = wv;
        }
    }
}

// ---------------- Kernel 4: edge MLP over flat adj-ordered list ----------------
// 10000 independent blocks, one 64-edge tile each; rows arrive grouped so
// prb[row] (bf16, bias folded) is L1-hot; pcb[col] is the single random
// stream. Gather phase batches its 16 packed words into 4 ds_write_b128
// (scalar b32 writes were an 8-way bank conflict -- the pinned 2.56e7).
__global__ __launch_bounds__(512, 4) void edge_kernel(
    const unsigned short* __restrict__ prb, const unsigned short* __restrict__ pcb,
    const int4* __restrict__ flat, const int* __restrict__ off,
    const float* __restrict__ w1p,
    const unsigned short* __restrict__ w2b, const float* __restrict__ b2,
    const float* __restrict__ w3, const float* __restrict__ b3v,
    float* __restrict__ attv) {
    __shared__ unsigned short buf[EPB * XST];
    __shared__ float part[8][EPB];
    __shared__ float w1ps[256];
    __shared__ float dvals[EPB], emv[EPB];
    __shared__ int ridx[EPB], cidx[EPB];

    int tid = threadIdx.x;
    int eb = blockIdx.x * EPB;

    if (tid < EPB) {
        int count = off[N_NODES];
        int idx = eb + tid;
        int4 v;
        if (idx < count) v = flat[idx];
        else { v.x = 0; v.y = 0; v.z = 0; v.w = 0; }
        ridx[tid] = v.x; cidx[tid] = v.y;
        union { int i; float f; } a, bu; a.i = v.z; bu.i = v.w;
        dvals[tid] = a.f; emv[tid] = bu.f;
    }
    if (tid >= 64 && tid < 320) w1ps[tid - 64] = w1p[tid - 64];

    int wave = tid >> 6, lane = tid & 63;
    int lrow = lane & 15, quad = lane >> 4;
    int n2 = wave * 16 + lrow;
    float bias2 = b2[n2];
    float w3v = w3[n2];

    __syncthreads();

    // ---- gather + layer-1 epilogue: thread (ge = tid>>3, cb = tid&7) owns one
    // 32-neuron chunk of one edge. Pairs (o, o+16) pack to the permuted
    // position matching w2b's k-order. All 16 words buffered, then 4x b128.
    {
        int ge = tid >> 3, cb = tid & 7;
        const unsigned short* prow = prb + (size_t)ridx[ge] * 256 + cb * 32;
        const unsigned short* pcp  = pcb + (size_t)cidx[ge] * 256 + cb * 32;
        float d = dvals[ge];
        const float* wp = &w1ps[cb * 32];
        unsigned u[16];

        bf16x8 pA = *(const bf16x8*)&prow[0];
        bf16x8 pB = *(const bf16x8*)&prow[16];
        bf16x8 qA = *(const bf16x8*)&pcp[0];
        bf16x8 qB = *(const bf16x8*)&pcp[16];
#pragma unroll
        for (int l = 0; l < 8; ++l) {
            float s0 = bf2f((unsigned short)pA[l]) + bf2f((unsigned short)qA[l]) + d * wp[2 * l];
            float s1 = bf2f((unsigned short)pB[l]) + bf2f((unsigned short)qB[l]) + d * wp[2 * l + 1];
            u[l] = pack_bf16(fsilu(s0), fsilu(s1));
        }
        pA = *(const bf16x8*)&prow[8];
        pB = *(const bf16x8*)&prow[24];
        qA = *(const bf16x8*)&pcp[8];
        qB = *(const bf16x8*)&pcp[24];
#pragma unroll
        for (int l = 0; l < 8; ++l) {
            float s0 = bf2f((unsigned short)pA[l]) + bf2f((unsigned short)qA[l]) + d * wp[16 + 2 * l];
            float s1 = bf2f((unsigned short)pB[l]) + bf2f((unsigned short)qB[l]) + d * wp[16 + 2 * l + 1];
            u[8 + l] = pack_bf16(fsilu(s0), fsilu(s1));
        }
        u32x4* w4 = (u32x4*)&buf[ge * XST + cb * 32];
        u32x4 v0 = {u[0], u[1], u[2], u[3]};
        u32x4 v1 = {u[4], u[5], u[6], u[7]};
        u32x4 v2 = {u[8], u[9], u[10], u[11]};
        u32x4 v3 = {u[12], u[13], u[14], u[15]};
        w4[0] = v0; w4[1] = v1; w4[2] = v2; w4[3] = v3;
    }
    __syncthreads();

    // ---- layer 2: wave covers 16 of 128 N2 (k-order permuted on both sides)
    f32x4 zz = {0.f, 0.f, 0.f, 0.f};
    f32x4 acc2[4];
#pragma unroll
    for (int mt = 0; mt < 4; ++mt) acc2[mt] = zz;

    for (int kk = 0; kk < 8; ++kk) {
        int ka = kk * 32 + quad * 8;
        bf16x8 bfrag = *(const bf16x8*)&w2b[(size_t)n2 * 256 + ka];
#pragma unroll
        for (int mt = 0; mt < 4; ++mt) {
            bf16x8 a = *(bf16x8*)&buf[(mt * 16 + lrow) * XST + ka];
            acc2[mt] = __builtin_amdgcn_mfma_f32_16x16x32_bf16(a, bfrag, acc2[mt], 0, 0, 0);
        }
    }

    // ---- layer 3 in registers
    float s[4][4];
#pragma unroll
    for (int mt = 0; mt < 4; ++mt)
#pragma unroll
        for (int r = 0; r < 4; ++r)
            s[mt][r] = fsilu(acc2[mt][r] + bias2) * w3v;
#pragma unroll
    for (int off2 = 1; off2 < 16; off2 <<= 1) {
#pragma unroll
        for (int mt = 0; mt < 4; ++mt)
#pragma unroll
            for (int r = 0; r < 4; ++r)
                s[mt][r] += __shfl_xor(s[mt][r], off2);
    }
    if (lrow == 0) {
#pragma unroll
        for (int mt = 0; mt < 4; ++mt)
#pragma unroll
            for (int r = 0; r < 4; ++r)
                part[wave][mt * 16 + quad * 4 + r] = s[mt][r];
    }
    __syncthreads();

    if (tid < EPB) {
        float ssum = b3v[0];
#pragma unroll
        for (int w = 0; w < 8; ++w) ssum += part[w][tid];
        attv[eb + tid] = fsig(ssum) * emv[tid];
    }
}

// ---------------- Kernel 5: aggregate + node MLP + LNs ----------------
__global__ __launch_bounds__(256) void node_kernel(
    const float* __restrict__ attv, const int* __restrict__ adjc,
    const int* __restrict__ cnt, const int* __restrict__ off,
    const unsigned short* __restrict__ xb,
    const float* __restrict__ x,
    const float* __restrict__ w1, const float* __restrict__ bb1,
    const float* __restrict__ lng, const float* __restrict__ lnb,
    const float* __restrict__ w2, const float* __restrict__ bb2,
    const float* __restrict__ gF, const float* __restrict__ bF,
    float* __restrict__ out, int E) {
    __shared__ float atts[NPB][CAP];
    __shared__ int   cols[NPB][CAP];
    __shared__ float outv[NPB][128];
    __shared__ float bufs[NPB][128];
    __shared__ float mu_s[NPB], rs_s[NPB];
    __shared__ int cnts[NPB];

    int t = threadIdx.x;
    int n0 = blockIdx.x * NPB;

    if (t < NPB) { int c = cnt[n0 + t]; cnts[t] = c > CAP ? CAP : c; }
    __syncthreads();

    {
        int jg = t >> 5, l = t & 31;
        int c = cnts[jg];
        const int* al = adjc + (size_t)(n0 + jg) * CAP;
        const float* av = attv + off[n0 + jg];
        for (int i = l; i < c; i += 32) {
            atts[jg][i] = av[i];
            cols[jg][i] = al[i];
        }
    }
    __syncthreads();

    int w = t >> 6, lane = t & 63;
#pragma unroll
    for (int jj = 0; jj < 2; ++jj) {
        int j = w * 2 + jj;
        int c = cnts[j];
        float lo0 = 0.f, hi0 = 0.f, lo1 = 0.f, hi1 = 0.f;
        float lo2 = 0.f, hi2 = 0.f, lo3 = 0.f, hi3 = 0.f;
        int i = 0;
        for (; i + 3 < c; i += 4) {
            unsigned u0 = *(const unsigned*)&xb[(size_t)cols[j][i]     * DIM + lane * 2];
            unsigned u1 = *(const unsigned*)&xb[(size_t)cols[j][i + 1] * DIM + lane * 2];
            unsigned u2 = *(const unsigned*)&xb[(size_t)cols[j][i + 2] * DIM + lane * 2];
            unsigned u3 = *(const unsigned*)&xb[(size_t)cols[j][i + 3] * DIM + lane * 2];
            float w0 = atts[j][i], w1v = atts[j][i + 1], w2v = atts[j][i + 2], w3v = atts[j][i + 3];
            lo0 += w0 * bf2f((unsigned short)(u0 & 0xffff)); hi0 += w0 * bf2f((unsigned short)(u0 >> 16));
            lo1 += w1v * bf2f((unsigned short)(u1 & 0xffff)); hi1 += w1v * bf2f((unsigned short)(u1 >> 16));
            lo2 += w2v * bf2f((unsigned short)(u2 & 0xffff)); hi2 += w2v * bf2f((unsigned short)(u2 >> 16));
            lo3 += w3v * bf2f((unsigned short)(u3 & 0xffff)); hi3 += w3v * bf2f((unsigned short)(u3 >> 16));
        }
        for (; i < c; ++i) {
            unsigned u0 = *(const unsigned*)&xb[(size_t)cols[j][i] * DIM + lane * 2];
            float w0 = atts[j][i];
            lo0 += w0 * bf2f((unsigned short)(u0 & 0xffff));
            hi0 += w0 * bf2f((unsigned short)(u0 >> 16));
        }
        outv[j][lane * 2]     = ((lo0 + lo1) + (lo2 + lo3)) * 0.01f;
        outv[j][lane * 2 + 1] = ((hi0 + hi1) + (hi2 + hi3)) * 0.01f;
    }
    __syncthreads();

    int h = t >> 7, ch = t & 127;
    float xres[4];
#pragma unroll
    for (int jj = 0; jj < 4; ++jj)
        xres[jj] = x[(size_t)(n0 + h * 4 + jj) * DIM + ch];

    float a1[4] = {0, 0, 0, 0};
    for (int kc = 0; kc < 128; kc += 4) {
        float4 wv = *(const float4*)&w1[(size_t)ch * DIM + kc];
#pragma unroll
        for (int jj = 0; jj < 4; ++jj) {
            int j = h * 4 + jj;
            float4 ov = *(const float4*)&outv[j][kc];
            a1[jj] += wv.x * ov.x + wv.y * ov.y + wv.z * ov.z + wv.w * ov.w;
        }
    }
    float bias1 = bb1[ch];
#pragma unroll
    for (int jj = 0; jj < 4; ++jj) bufs[h * 4 + jj][ch] = a1[jj] + bias1;
    __syncthreads();

    {
        int j = t >> 5, l = t & 31;
        float s = 0.f, qq = 0.f;
#pragma unroll
        for (int i = 0; i < 4; ++i) { float v = bufs[j][l + 32 * i]; s += v; qq += v * v; }
#pragma unroll
        for (int off2 = 16; off2; off2 >>= 1) { s += __shfl_xor(s, off2); qq += __shfl_xor(qq, off2); }
        if (l == 0) {
            float mu = s * (1.f / 128.f);
            float var = qq * (1.f / 128.f) - mu * mu;
            mu_s[j] = mu; rs_s[j] = __builtin_amdgcn_rsqf(var + 1e-5f);
        }
    }
    __syncthreads();

    float g = lng[ch], bb = lnb[ch];
    float h2[4];
#pragma unroll
    for (int jj = 0; jj < 4; ++jj) {
        int j = h * 4 + jj;
        h2[jj] = fsilu((bufs[j][ch] - mu_s[j]) * rs_s[j] * g + bb);
    }
    __syncthreads();
#pragma unroll
    for (int jj = 0; jj < 4; ++jj) bufs[h * 4 + jj][ch] = h2[jj];
    __syncthreads();

    float a3[4] = {0, 0, 0, 0};
    for (int kc = 0; kc < 128; kc += 4) {
        float4 wv = *(const float4*)&w2[(size_t)ch * DIM + kc];
#pragma unroll
        for (int jj = 0; jj < 4; ++jj) {
            int j = h * 4 + jj;
            float4 bv = *(const float4*)&bufs[j][kc];
            a3[jj] += wv.x * bv.x + wv.y * bv.y + wv.z * bv.z + wv.w * bv.w;
        }
    }
    float bias2 = bb2[ch];
    float hh[4];
#pragma unroll
    for (int jj = 0; jj < 4; ++jj) hh[jj] = a3[jj] + bias2 + xres[jj];
    __syncthreads();
#pragma unroll
    for (int jj = 0; jj < 4; ++jj) bufs[h * 4 + jj][ch] = hh[jj];
    __syncthreads();

    {
        int j = t >> 5, l = t & 31;
        float s = 0.f, qq = 0.f;
#pragma unroll
        for (int i = 0; i < 4; ++i) { float v = bufs[j][l + 32 * i]; s += v; qq += v * v; }
#pragma unroll
        for (int off2 = 16; off2; off2 >>= 1) { s += __shfl_xor(s, off2); qq += __shfl_xor(qq, off2); }
        if (l == 0) {
            float mu = s * (1.f / 128.f);
            float var = qq * (1.f / 128.f) - mu * mu;
            mu_s[j] = mu; rs_s[j] = __builtin_amdgcn_rsqf(var + 1e-5f);
        }
    }
    __syncthreads();

    float gf = gF[ch], bf = bF[ch];
#pragma unroll
    for (int jj = 0; jj < 4; ++jj) {
        int j = h * 4 + jj;
        float y = (hh[jj] - mu_s[j]) * rs_s[j] * gf + bf;
        out[(size_t)(n0 + j) * DIM + ch] = fsilu(y);
    }
}

extern "C" void kernel_launch(void* const* d_in, const int* in_sizes, int n_in,
                              void* d_out, int out_size, void* d_ws, size_t ws_size,
                              hipStream_t stream) {
    const float* h         = (const float*)d_in[0];
    const float* distances = (const float*)d_in[1];
    const float* edge_mask = (const float*)d_in[3];
    const float* lin_w     = (const float*)d_in[4];
    const float* lin_b     = (const float*)d_in[5];
    const float* att_w1    = (const float*)d_in[6];
    const float* att_b1    = (const float*)d_in[7];
    const float* att_w2    = (const float*)d_in[8];
    const float* att_b2    = (const float*)d_in[9];
    const float* att_w3    = (const float*)d_in[10];
    const float* att_b3    = (const float*)d_in[11];
    const float* nm_w1     = (const float*)d_in[12];
    const float* nm_b1     = (const float*)d_in[13];
    const float* nm_ln_g   = (const float*)d_in[14];
    const float* nm_ln_b   = (const float*)d_in[15];
    const float* nm_w2     = (const float*)d_in[16];
    const float* nm_b2     = (const float*)d_in[17];
    const float* ln_g      = (const float*)d_in[18];
    const float* ln_b      = (const float*)d_in[19];
    const int*   edges     = (const int*)d_in[20];
    float* out = (float*)d_out;

    const int N = N_NODES, E = E_EDGES;

    char* ws = (char*)d_ws;
    float* x            = (float*)ws;            ws += (size_t)N * DIM * 4;
    unsigned short* xb  = (unsigned short*)ws;   ws += (size_t)N * DIM * 2;
    int* cnt            = (int*)ws;              ws += (size_t)N * 4;
    int* off            = (int*)ws;              ws += (size_t)(N + 4) * 4;
    int* adjc           = (int*)ws;              ws += (size_t)N * CAP * 4;
    float2* dm          = (float2*)ws;           ws += (size_t)N * CAP * 8;
    float* attv         = (float*)ws;            ws += (size_t)E * 4;
    unsigned short* w1b = (unsigned short*)ws;   ws += 256 * 256 * 2;
    float* w1p          = (float*)ws;            ws += 256 * 4;
    unsigned short* w2b = (unsigned short*)ws;   ws += 128 * 256 * 2;
    unsigned short* prb = (unsigned short*)ws;   ws += (size_t)N * 256 * 2;
    unsigned short* pcb = (unsigned short*)ws;   ws += (size_t)N * 256 * 2;
    int4* flat          = (int4*)ws;             ws += (size_t)E * 16;

    hipMemsetAsync(cnt, 0, (size_t)N * 4, stream);

    pre_kernel<<<PRE_PREP_BLOCKS + PRE_LIN_BLOCKS + PRE_ADJ_BLOCKS, 256, 0, stream>>>(
        att_w1, att_w2, w1b, w1p, w2b,
        h, lin_w, lin_b, x, xb,
        edges, distances, edge_mask, cnt, adjc, dm, E);
    scan_kernel<<<1, 1024, 0, stream>>>(cnt, off);
    mid_kernel<<<MID_PRC_BLOCKS + MID_FLAT_BLOCKS, 256, 0, stream>>>(
        xb, w1b, att_b1, prb, pcb, adjc, dm, cnt, off, flat);
    edge_kernel<<<E / EPB, 512, 0, stream>>>(prb, pcb, flat, off,
                                             w1p, w2b, att_b2,
                                             att_w3, att_b3, attv);
    node_kernel<<<N / NPB, 256, 0, stream>>>(attv, adjc, cnt, off, xb, x,
                                             nm_w1, nm_b1, nm_ln_g, nm_ln_b,
                                             nm_w2, nm_b2, ln_g, ln_b, out, E);
}